// Round 5
// baseline (371.517 us; speedup 1.0000x reference)
//
#include <hip/hip_runtime.h>
#include <hip/hip_bf16.h>

#define H 19
#define Bv 2
#define Sv 2048
#define Dv 1024
#define DHv 64
#define KK2 (2*H*DHv)   // 2432
#define QSCALE 0.125f

typedef __bf16 bf16x8 __attribute__((ext_vector_type(8)));
typedef float f32x4 __attribute__((ext_vector_type(4)));

__device__ __forceinline__ ushort f2bf(float f) {
    uint u = __float_as_uint(f);
    u = (u + 0x7fffu + ((u >> 16) & 1u)) >> 16;
    return (ushort)u;
}

__device__ __forceinline__ uint cvtpk(float lo, float hi) {
    uint r;
    asm("v_cvt_pk_bf16_f32 %0, %1, %2" : "=v"(r) : "v"(lo), "v"(hi));
    return r;
}

// async global->LDS, 16B per lane; dest = wave-uniform base + lane*16
__device__ __forceinline__ void gll16(const ushort* g, ushort* l) {
    __builtin_amdgcn_global_load_lds(
        (const __attribute__((address_space(1))) unsigned int*)g,
        (__attribute__((address_space(3))) unsigned int*)l, 16, 0, 0);
}

// ---------------- prep: x -> bf16 ----------------
__global__ __launch_bounds__(256) void prep_x(const float* __restrict__ x,
                                              ushort* __restrict__ xbf) {
    int idx = (blockIdx.x*256 + threadIdx.x)*8;
    float4 a = *(const float4*)&x[idx];
    float4 b = *(const float4*)&x[idx+4];
    uint4 o;
    o.x = cvtpk(a.x, a.y);
    o.y = cvtpk(a.z, a.w);
    o.z = cvtpk(b.x, b.y);
    o.w = cvtpk(b.z, b.w);
    *(uint4*)&xbf[idx] = o;
}

// ---------------- prep: pack+transpose qkv weights -> wpackT [H][192][1024] bf16 ----------------
__global__ __launch_bounds__(256) void prep_w(const float* __restrict__ wq,
                                              const float* __restrict__ wk,
                                              const float* __restrict__ wv,
                                              ushort* __restrict__ wpackT) {
    const int dt = blockIdx.x, t = blockIdx.y, h = blockIdx.z;
    const float* w = (t == 0) ? wq : (t == 1) ? wk : wv;
    w += (size_t)h*Dv*DHv;
    __shared__ ushort T[64*65];
    const int tid = threadIdx.x;
    int row = tid >> 2, c4 = tid & 3;
    #pragma unroll
    for (int q4 = 0; q4 < 4; ++q4) {
        float4 v = *(const float4*)&w[(size_t)(dt*64+row)*DHv + c4*16 + q4*4];
        T[(c4*16 + q4*4 + 0)*65 + row] = f2bf(v.x);
        T[(c4*16 + q4*4 + 1)*65 + row] = f2bf(v.y);
        T[(c4*16 + q4*4 + 2)*65 + row] = f2bf(v.z);
        T[(c4*16 + q4*4 + 3)*65 + row] = f2bf(v.w);
    }
    __syncthreads();
    #pragma unroll
    for (int i = 0; i < 2; ++i) {
        int f = tid + i*256;
        int e = f >> 3, c = f & 7;
        uint u[4];
        #pragma unroll
        for (int j = 0; j < 4; ++j) {
            uint lo = T[e*65 + c*8 + 2*j];
            uint hi = T[e*65 + c*8 + 2*j + 1];
            u[j] = lo | (hi << 16);
        }
        *(uint4*)&wpackT[((size_t)h*192 + t*64 + e)*Dv + dt*64 + c*8] = make_uint4(u[0],u[1],u[2],u[3]);
    }
}

// ---------------- prep: w_mix -> transposed bf16 [e][f] ----------------
__global__ __launch_bounds__(256) void prep_wmix(const float* __restrict__ wm,
                                                 ushort* __restrict__ wmixT) {
    int tid = threadIdx.x;
    int e = tid >> 2, f4 = tid & 3;
    #pragma unroll
    for (int j = 0; j < 16; ++j) {
        int f = f4*16 + j;
        wmixT[e*64 + f] = f2bf(wm[f*64 + e]);
    }
}

// ---------------- prep: woTcat [1024 n][2432 k] = [w_o^T | (adj-folded w_o)^T] ----------------
__global__ __launch_bounds__(256) void prep_wo2(const float* __restrict__ wo,
                                                const float* __restrict__ adj,
                                                ushort* __restrict__ woTcat) {
    const int nt = blockIdx.x;   // 16 n-tiles
    const int g  = blockIdx.y;   // 19 e-tiles
    const int tid = threadIdx.x;
    const int e = tid >> 2, n4 = tid & 3;
    float acc[16];
    float part1[16];
    #pragma unroll
    for (int j = 0; j < 16; ++j) { acc[j] = 0.f; part1[j] = 0.f; }
    for (int h2 = 0; h2 < H; ++h2) {
        float a = adj[h2*H + g];
        const float* rp = wo + (size_t)(h2*64 + e)*Dv + nt*64 + n4*16;
        #pragma unroll
        for (int j4 = 0; j4 < 4; ++j4) {
            float4 v = *(const float4*)&rp[j4*4];
            acc[j4*4+0] += a*v.x; acc[j4*4+1] += a*v.y;
            acc[j4*4+2] += a*v.z; acc[j4*4+3] += a*v.w;
            if (h2 == g) {
                part1[j4*4+0] = v.x; part1[j4*4+1] = v.y;
                part1[j4*4+2] = v.z; part1[j4*4+3] = v.w;
            }
        }
    }
    #pragma unroll
    for (int j = 0; j < 16; ++j) {
        int n = nt*64 + n4*16 + j;
        woTcat[(size_t)n*KK2 + g*64 + e]            = f2bf(part1[j]);
        woTcat[(size_t)n*KK2 + H*DHv + g*64 + e]    = f2bf(acc[j]);
    }
}

// ---------------- bias: relu(coords@wb1+bb1)@wb2+bb2 -> [H,DH] fp32 ----------------
__global__ void bias_kernel(const float* __restrict__ coords,
                            const float* __restrict__ wb1,
                            const float* __restrict__ bb1,
                            const float* __restrict__ wb2,
                            const float* __restrict__ bb2,
                            float* __restrict__ bias) {
    int h = blockIdx.x;
    int e = threadIdx.x;
    float c0 = coords[h*2 + 0];
    float c1 = coords[h*2 + 1];
    float acc = bb2[e];
    for (int d = 0; d < Dv; ++d) {
        float hd = c0*wb1[d] + c1*wb1[Dv + d] + bb1[d];
        hd = fmaxf(hd, 0.0f);
        acc += hd * wb2[d*DHv + e];
    }
    bias[h*DHv + e] = acc;
}

// ---------------- QKV projection, bf16 MFMA ----------------
__global__ __launch_bounds__(256) void qkv_mfma(const ushort* __restrict__ xbf,
                                                const ushort* __restrict__ wpackT,
                                                const float* __restrict__ bias,
                                                ushort* __restrict__ qbf,
                                                ushort* __restrict__ kbf,
                                                ushort* __restrict__ vtbf) {
    const int mt = blockIdx.x, h = blockIdx.y;
    const int m0 = mt*64;
    const int tid = threadIdx.x;
    const int w = tid >> 6, lane = tid & 63;
    const int g = lane >> 4, r = lane & 15;

    __shared__ char lds[8192 + 24576];
    char* Xs = lds;
    char* Ws = lds + 8192;
    ushort* VtL = (ushort*)lds;

    f32x4 acc[4][3];
    const f32x4 zf = {0.f,0.f,0.f,0.f};
    #pragma unroll
    for (int m = 0; m < 4; ++m)
        #pragma unroll
        for (int n = 0; n < 3; ++n) acc[m][n] = zf;

    const ushort* xb = xbf + (size_t)m0*Dv;
    const ushort* wb = wpackT + (size_t)h*192*Dv;

    for (int kt = 0; kt < Dv; kt += 64) {
        __syncthreads();
        #pragma unroll
        for (int i = 0; i < 2; ++i) {
            int f = tid + i*256;
            int row = f >> 3, c = f & 7;
            *(bf16x8*)(Xs + row*128 + ((c*16) ^ ((row & 7) << 4))) =
                *(const bf16x8*)(xb + (size_t)row*Dv + kt + c*8);
        }
        #pragma unroll
        for (int i = 0; i < 6; ++i) {
            int f = tid + i*256;
            int row = f >> 3, c = f & 7;
            *(bf16x8*)(Ws + row*128 + ((c*16) ^ ((row & 7) << 4))) =
                *(const bf16x8*)(wb + (size_t)row*Dv + kt + c*8);
        }
        __syncthreads();
        #pragma unroll
        for (int kk = 0; kk < 2; ++kk) {
            bf16x8 a[4], bfr[3];
            #pragma unroll
            for (int m = 0; m < 4; ++m) {
                int row = m*16 + r;
                a[m] = *(const bf16x8*)(Xs + row*128 + (((kk*32 + g*8)*2) ^ ((row & 7) << 4)));
            }
            #pragma unroll
            for (int n = 0; n < 3; ++n) {
                int row = (w*3 + n)*16 + r;
                bfr[n] = *(const bf16x8*)(Ws + row*128 + (((kk*32 + g*8)*2) ^ ((row & 7) << 4)));
            }
            #pragma unroll
            for (int m = 0; m < 4; ++m)
                #pragma unroll
                for (int n = 0; n < 3; ++n)
                    acc[m][n] = __builtin_amdgcn_mfma_f32_16x16x32_bf16(a[m], bfr[n], acc[m][n], 0, 0, 0);
        }
    }

    __syncthreads();

    const int bb = m0 >> 11;
    const int s0 = m0 & 2047;
    #pragma unroll
    for (int m = 0; m < 4; ++m) {
        #pragma unroll
        for (int n = 0; n < 3; ++n) {
            int ng = w*3 + n;
            int t = ng >> 2;
            int e = (ng & 3)*16 + r;
            if (t == 0) {
                float bvv = bias[h*DHv + e];
                #pragma unroll
                for (int reg = 0; reg < 4; ++reg) {
                    int ss = s0 + m*16 + g*4 + reg;
                    qbf[(((size_t)bb*H + h)*Sv + ss)*DHv + e] = f2bf((acc[m][n][reg] + bvv)*QSCALE);
                }
            } else if (t == 1) {
                #pragma unroll
                for (int reg = 0; reg < 4; ++reg) {
                    int ss = s0 + m*16 + g*4 + reg;
                    kbf[(((size_t)bb*H + h)*Sv + ss)*DHv + e] = f2bf(acc[m][n][reg]);
                }
            } else {
                #pragma unroll
                for (int reg = 0; reg < 4; ++reg) {
                    int sl = m*16 + g*4 + reg;
                    VtL[e*66 + sl] = f2bf(acc[m][n][reg]);
                }
            }
        }
    }
    __syncthreads();
    #pragma unroll
    for (int i = 0; i < 2; ++i) {
        int f = tid + i*256;
        int dh = f >> 3, sc = f & 7;
        uint u[4];
        #pragma unroll
        for (int j = 0; j < 4; ++j) {
            uint lo = VtL[dh*66 + sc*8 + 2*j];
            uint hi = VtL[dh*66 + sc*8 + 2*j + 1];
            u[j] = lo | (hi << 16);
        }
        *(uint4*)&vtbf[(((size_t)bb*H + h)*DHv + dh)*Sv + s0 + sc*8] = make_uint4(u[0],u[1],u[2],u[3]);
    }
}

// ---------------- MFMA flash attention + fused GNN msg ----------------
// 128 q-rows/block, 4 waves x 32 q-rows (2 groups of 16). Swapped-operand softmax.
// Q pre-scaled bf16 [B,H,S,DH]; K bf16 [B,H,S,DH]; V bf16 [B,H,DH,S].
// Outputs: heads bf16 [B,H,S,DH], msg = relu(heads@w_mix) bf16 [B,H,S,DH].
__global__ __launch_bounds__(256) void attn_mfma(const ushort* __restrict__ qg,
                                                 const ushort* __restrict__ kg,
                                                 const ushort* __restrict__ vtg,
                                                 const ushort* __restrict__ wmixT,
                                                 ushort* __restrict__ headsbf,
                                                 ushort* __restrict__ msgbf) {
    const int qt = blockIdx.x, h = blockIdx.y, b = blockIdx.z;
    const int tid = threadIdx.x;
    const int w = tid >> 6, lane = tid & 63;
    const int g = lane >> 4, r = lane & 15;

    __shared__ ushort Ks[4096];       // [kv 64][dh 64] swizzled
    __shared__ ushort Vs[4096];       // [dh 64][kv 64] swizzled
    __shared__ ushort Ps[4][2048];    // per-wave, 2 groups x [q 16][kv 64] swizzled

    const size_t bh = (size_t)b*H + h;
    const ushort* kb = kg + bh*Sv*DHv;
    const ushort* vb = vtg + bh*DHv*Sv;

    // Q fragments: [grp][kk]
    bf16x8 qf[2][2];
    #pragma unroll
    for (int grp = 0; grp < 2; ++grp) {
        const ushort* qb = qg + (bh*Sv + qt*128 + w*32 + grp*16 + r)*DHv;
        qf[grp][0] = *(const bf16x8*)(qb + g*8);
        qf[grp][1] = *(const bf16x8*)(qb + 32 + g*8);
    }

    float m_run[2] = {-1e30f, -1e30f}, l_run[2] = {0.f, 0.f};
    f32x4 o[2][4];
    const f32x4 zf = {0.f,0.f,0.f,0.f};
    #pragma unroll
    for (int grp = 0; grp < 2; ++grp)
        #pragma unroll
        for (int n = 0; n < 4; ++n) o[grp][n] = zf;

    const int srow = lane >> 3;   // 0..7
    const int scl  = lane & 7;

    for (int jt = 0; jt < Sv/64; ++jt) {
        __syncthreads();
        // stage K [64 kv][64 dh] and V^T [64 dh][64 kv]: linear LDS dest,
        // inverse-swizzled global source (rule #21)
        #pragma unroll
        for (int is = 0; is < 2; ++is) {
            int row = w*16 + is*8 + srow;
            int kcol = (scl ^ (row & 7)) * 8;
            gll16(kb + (size_t)(jt*64 + row)*DHv + kcol, &Ks[(w*16 + is*8)*64]);
            gll16(vb + (size_t)row*Sv + jt*64 + kcol, &Vs[(w*16 + is*8)*64]);
        }
        asm volatile("s_waitcnt vmcnt(0)" ::: "memory");
        __syncthreads();

        // K fragments (shared by both q-groups)
        bf16x8 kf[2][4];
        #pragma unroll
        for (int kk = 0; kk < 2; ++kk)
            #pragma unroll
            for (int nt = 0; nt < 4; ++nt) {
                int kvrow = nt*16 + r;
                kf[kk][nt] = *(const bf16x8*)((const char*)Ks + kvrow*128 +
                                              ((kk*64 + g*16) ^ ((kvrow & 7) << 4)));
            }

        // scores SWAPPED: D[kv][q] = mfma(K, Q); lane holds q=r, kv = nt*16+g*4+reg
        f32x4 sc[2][4];
        #pragma unroll
        for (int grp = 0; grp < 2; ++grp) {
            sc[grp][0]=zf; sc[grp][1]=zf; sc[grp][2]=zf; sc[grp][3]=zf;
            #pragma unroll
            for (int kk = 0; kk < 2; ++kk)
                #pragma unroll
                for (int nt = 0; nt < 4; ++nt)
                    sc[grp][nt] = __builtin_amdgcn_mfma_f32_16x16x32_bf16(
                        kf[kk][nt], qf[grp][kk], sc[grp][nt], 0, 0, 0);
        }

        // softmax + P pack per group
        #pragma unroll
        for (int grp = 0; grp < 2; ++grp) {
            float pmax = sc[grp][0][0];
            #pragma unroll
            for (int nt = 0; nt < 4; ++nt)
                #pragma unroll
                for (int reg = 0; reg < 4; ++reg)
                    pmax = fmaxf(pmax, sc[grp][nt][reg]);
            pmax = fmaxf(pmax, __shfl_xor(pmax, 16));
            pmax = fmaxf(pmax, __shfl_xor(pmax, 32));

            if (__any(pmax > m_run[grp] + 8.0f)) {
                float mn = fmaxf(m_run[grp], pmax);
                float corr = __expf(m_run[grp] - mn);
                l_run[grp] *= corr;
                #pragma unroll
                for (int nt2 = 0; nt2 < 4; ++nt2) {
                    o[grp][nt2][0] *= corr; o[grp][nt2][1] *= corr;
                    o[grp][nt2][2] *= corr; o[grp][nt2][3] *= corr;
                }
                m_run[grp] = mn;
            }

            float lsum = 0.f;
            #pragma unroll
            for (int nt = 0; nt < 4; ++nt) {
                #pragma unroll
                for (int reg = 0; reg < 4; ++reg) {
                    float p = __expf(sc[grp][nt][reg] - m_run[grp]);
                    sc[grp][nt][reg] = p;
                    lsum += p;
                }
            }
            lsum += __shfl_xor(lsum, 16);
            lsum += __shfl_xor(lsum, 32);
            l_run[grp] += lsum;

            ushort* pw = &Ps[w][grp*1024];
            #pragma unroll
            for (int nt = 0; nt < 4; ++nt) {
                uint u0 = cvtpk(sc[grp][nt][0], sc[grp][nt][1]);
                uint u1 = cvtpk(sc[grp][nt][2], sc[grp][nt][3]);
                int chunk = (2*nt + (g >> 1)) ^ (r & 7);
                *(uint2*)((char*)pw + r*128 + (chunk << 4) + ((g & 1)*8)) = make_uint2(u0, u1);
            }
        }

        // V fragments (shared by both q-groups)
        bf16x8 vf[2][4];
        #pragma unroll
        for (int kk = 0; kk < 2; ++kk)
            #pragma unroll
            for (int nt2 = 0; nt2 < 4; ++nt2) {
                int dh = nt2*16 + r;
                vf[kk][nt2] = *(const bf16x8*)((const char*)Vs + dh*128 +
                                               ((kk*64 + g*16) ^ ((dh & 7) << 4)));
            }

        // PV SWAPPED: O^T[dh][q] = mfma(V^T, P)
        #pragma unroll
        for (int grp = 0; grp < 2; ++grp) {
            const ushort* pw = &Ps[w][grp*1024];
            #pragma unroll
            for (int kk = 0; kk < 2; ++kk) {
                bf16x8 pa = *(const bf16x8*)((const char*)pw + r*128 +
                                             (((kk*4 + g) ^ (r & 7)) << 4));
                #pragma unroll
                for (int nt2 = 0; nt2 < 4; ++nt2)
                    o[grp][nt2] = __builtin_amdgcn_mfma_f32_16x16x32_bf16(
                        vf[kk][nt2], pa, o[grp][nt2], 0, 0, 0);
            }
        }
    }

    // epilogue: normalize, write heads bf16, and stash heads^T tile in Ps for msg
    #pragma unroll
    for (int grp = 0; grp < 2; ++grp) {
        float inv = 1.0f / l_run[grp];
        ushort* hp = headsbf + (bh*Sv + qt*128 + w*32 + grp*16 + r)*DHv;
        ushort* pw = &Ps[w][grp*1024];
        #pragma unroll
        for (int nt2 = 0; nt2 < 4; ++nt2) {
            uint u0 = cvtpk(o[grp][nt2][0]*inv, o[grp][nt2][1]*inv);
            uint u1 = cvtpk(o[grp][nt2][2]*inv, o[grp][nt2][3]*inv);
            *(uint2*)(hp + nt2*16 + g*4) = make_uint2(u0, u1);
            int chunk = (2*nt2 + (g >> 1)) ^ (r & 7);
            *(uint2*)((char*)pw + r*128 + (chunk << 4) + ((g & 1)*8)) = make_uint2(u0, u1);
        }
    }

    // fused msg = relu(heads @ w_mix): msg^T = mfma(w_mix^T, heads^T)
    bf16x8 wm[2][4];
    #pragma unroll
    for (int kk = 0; kk < 2; ++kk)
        #pragma unroll
        for (int nt = 0; nt < 4; ++nt)
            wm[kk][nt] = *(const bf16x8*)(wmixT + (nt*16 + r)*64 + kk*32 + g*8);

    #pragma unroll
    for (int grp = 0; grp < 2; ++grp) {
        const ushort* pw = &Ps[w][grp*1024];
        f32x4 macc[4];
        macc[0]=zf; macc[1]=zf; macc[2]=zf; macc[3]=zf;
        #pragma unroll
        for (int kk = 0; kk < 2; ++kk) {
            bf16x8 pa = *(const bf16x8*)((const char*)pw + r*128 +
                                         (((kk*4 + g) ^ (r & 7)) << 4));
            #pragma unroll
            for (int nt = 0; nt < 4; ++nt)
                macc[nt] = __builtin_amdgcn_mfma_f32_16x16x32_bf16(wm[kk][nt], pa, macc[nt], 0, 0, 0);
        }
        ushort* mp = msgbf + (bh*Sv + qt*128 + w*32 + grp*16 + r)*DHv;
        #pragma unroll
        for (int nt = 0; nt < 4; ++nt) {
            uint u0 = cvtpk(fmaxf(macc[nt][0], 0.f), fmaxf(macc[nt][1], 0.f));
            uint u1 = cvtpk(fmaxf(macc[nt][2], 0.f), fmaxf(macc[nt][3], 0.f));
            *(uint2*)(mp + nt*16 + g*4) = make_uint2(u0, u1);
        }
    }
}

// ---------------- out projection: [heads|msg] (K=2432) @ woTcat -> out fp32 ----------------
__global__ __launch_bounds__(256) void out_mfma(const ushort* __restrict__ headsbf,
                                                const ushort* __restrict__ msgbf,
                                                const ushort* __restrict__ woTcat,
                                                float* __restrict__ out) {
    const int mt = blockIdx.x, nt2 = blockIdx.y;
    const int m0 = mt*64, n0 = nt2*128;
    const int tid = threadIdx.x;
    const int w = tid >> 6, lane = tid & 63;
    const int g = lane >> 4, r = lane & 15;

    __shared__ char lds[8192 + 16384];
    char* As = lds;
    char* Bs = lds + 8192;

    const int b = m0 >> 11;
    const int s0 = m0 & 2047;

    f32x4 acc[8];
    const f32x4 zf = {0.f,0.f,0.f,0.f};
    #pragma unroll
    for (int n = 0; n < 8; ++n) acc[n] = zf;

    for (int ktile = 0; ktile < KK2/64; ++ktile) {
        const int hh = (ktile < H) ? ktile : ktile - H;
        const ushort* asrc = ((ktile < H) ? headsbf : msgbf) +
                             ((size_t)((size_t)b*H + hh)*Sv + s0)*DHv;
        __syncthreads();
        #pragma unroll
        for (int i = 0; i < 2; ++i) {
            int f = tid + i*256;
            int row = f >> 3, c = f & 7;
            *(bf16x8*)(As + row*128 + ((c*16) ^ ((row & 7) << 4))) =
                *(const bf16x8*)(asrc + (size_t)row*DHv + c*8);
        }
        #pragma unroll
        for (int i = 0; i < 4; ++i) {
            int f = tid + i*256;
            int row = f >> 3, c = f & 7;
            *(bf16x8*)(Bs + row*128 + ((c*16) ^ ((row & 7) << 4))) =
                *(const bf16x8*)(woTcat + (size_t)(n0 + row)*KK2 + ktile*64 + c*8);
        }
        __syncthreads();
        #pragma unroll
        for (int kk = 0; kk < 2; ++kk) {
            int arow = w*16 + r;
            bf16x8 a = *(const bf16x8*)(As + arow*128 + (((kk*32 + g*8)*2) ^ ((arow & 7) << 4)));
            #pragma unroll
            for (int n = 0; n < 8; ++n) {
                int brow = n*16 + r;
                bf16x8 bfr = *(const bf16x8*)(Bs + brow*128 + (((kk*32 + g*8)*2) ^ ((brow & 7) << 4)));
                acc[n] = __builtin_amdgcn_mfma_f32_16x16x32_bf16(a, bfr, acc[n], 0, 0, 0);
            }
        }
    }

    #pragma unroll
    for (int n = 0; n < 8; ++n) {
        #pragma unroll
        for (int reg = 0; reg < 4; ++reg) {
            int grow = m0 + w*16 + g*4 + reg;
            out[(size_t)grow*Dv + n0 + n*16 + r] = acc[n][reg];
        }
    }
}

extern "C" void kernel_launch(void* const* d_in, const int* in_sizes, int n_in,
                              void* d_out, int out_size, void* d_ws, size_t ws_size,
                              hipStream_t stream) {
    const float* x      = (const float*)d_in[0];
    const float* coords = (const float*)d_in[1];
    const float* w_q    = (const float*)d_in[2];
    const float* w_k    = (const float*)d_in[3];
    const float* w_v    = (const float*)d_in[4];
    const float* wb1    = (const float*)d_in[5];
    const float* bb1    = (const float*)d_in[6];
    const float* wb2    = (const float*)d_in[7];
    const float* bb2    = (const float*)d_in[8];
    const float* w_mix  = (const float*)d_in[9];
    const float* adj    = (const float*)d_in[10];
    const float* w_o    = (const float*)d_in[11];

    char* ws = (char*)d_ws;
    const size_t QKV_BYTES = (size_t)Bv*H*Sv*DHv*2;   // 9,961,472
    const size_t XBF_BYTES = (size_t)Bv*Sv*Dv*2;      // 8,388,608
    const size_t WPK_BYTES = (size_t)H*192*Dv*2;      // 7,471,104

    size_t off = 0;
    float*  bias  = (float*)(ws + off);  off += 16384;
    ushort* qbf   = (ushort*)(ws + off); off += QKV_BYTES;
    ushort* kbf   = (ushort*)(ws + off); off += QKV_BYTES;
    ushort* vtbf  = (ushort*)(ws + off); off += QKV_BYTES;
    ushort* hdbf  = (ushort*)(ws + off); off += QKV_BYTES;
    ushort* xbf   = (ushort*)(ws + off);
    ushort* msgbf = xbf;                              // aliases xbf+wpkT (dead after qkv)
    off += XBF_BYTES;
    ushort* wpkT  = (ushort*)(ws + off); off += WPK_BYTES;
    ushort* wmixT = (ushort*)(ws + off); off += 8192;
    ushort* woTc  = (ushort*)(ws + off); off += (size_t)Dv*KK2*2;
    float*  out   = (float*)d_out;

    prep_x<<<(Bv*Sv*Dv)/(256*8), 256, 0, stream>>>(x, xbf);
    prep_w<<<dim3(16, 3, H), 256, 0, stream>>>(w_q, w_k, w_v, wpkT);
    prep_wmix<<<1, 256, 0, stream>>>(w_mix, wmixT);
    prep_wo2<<<dim3(16, H), 256, 0, stream>>>(w_o, adj, woTc);
    bias_kernel<<<H, DHv, 0, stream>>>(coords, wb1, bb1, wb2, bb2, bias);
    qkv_mfma<<<dim3(64, H), 256, 0, stream>>>(xbf, wpkT, bias, qbf, kbf, vtbf);
    attn_mfma<<<dim3(Sv/128, H, Bv), 256, 0, stream>>>(qbf, kbf, vtbf, wmixT, hdbf, msgbf);
    out_mfma<<<dim3(64, 8), 256, 0, stream>>>(hdbf, msgbf, woTc, out);
}

// Round 6
// 356.881 us; speedup vs baseline: 1.0410x; 1.0410x over previous
//
#include <hip/hip_runtime.h>
#include <hip/hip_bf16.h>

#define H 19
#define Bv 2
#define Sv 2048
#define Dv 1024
#define DHv 64
#define KK2 (2*H*DHv)   // 2432
// 0.125 * log2(e): scores come out of QK^T already in log2 domain
#define QSCALE 0.1803368801111204f

typedef __bf16 bf16x8 __attribute__((ext_vector_type(8)));
typedef float f32x4 __attribute__((ext_vector_type(4)));

__device__ __forceinline__ ushort f2bf(float f) {
    uint u = __float_as_uint(f);
    u = (u + 0x7fffu + ((u >> 16) & 1u)) >> 16;
    return (ushort)u;
}

__device__ __forceinline__ uint cvtpk(float lo, float hi) {
    uint r;
    asm("v_cvt_pk_bf16_f32 %0, %1, %2" : "=v"(r) : "v"(lo), "v"(hi));
    return r;
}

__device__ __forceinline__ float fexp2(float x) {
#if __has_builtin(__builtin_amdgcn_exp2f)
    return __builtin_amdgcn_exp2f(x);
#else
    return exp2f(x);
#endif
}

// async global->LDS, 16B per lane; dest = wave-uniform base + lane*16
__device__ __forceinline__ void gll16(const ushort* g, ushort* l) {
    __builtin_amdgcn_global_load_lds(
        (const __attribute__((address_space(1))) unsigned int*)g,
        (__attribute__((address_space(3))) unsigned int*)l, 16, 0, 0);
}

// ---------------- merged prep: x->bf16, wqkv pack+T, wmixT, woTcat, bias ----------------
#define PX_N 2048
#define PW_N 912
#define PWMIX_AT (PX_N + PW_N)            // 2960
#define PWO2_AT  (PWMIX_AT + 1)           // 2961
#define PBIAS_AT (PWO2_AT + 304)          // 3265
#define PREP_N   (PBIAS_AT + H)           // 3284

__global__ __launch_bounds__(256) void prep_all(
    const float* __restrict__ x,  const float* __restrict__ wq,
    const float* __restrict__ wk, const float* __restrict__ wv,
    const float* __restrict__ wo, const float* __restrict__ adj,
    const float* __restrict__ wm, const float* __restrict__ coords,
    const float* __restrict__ wb1, const float* __restrict__ bb1,
    const float* __restrict__ wb2, const float* __restrict__ bb2,
    ushort* __restrict__ xbf, ushort* __restrict__ wpackT,
    ushort* __restrict__ wmixT, ushort* __restrict__ woTcat,
    float* __restrict__ bias)
{
    __shared__ char psm[8448];
    const int bid = blockIdx.x;
    const int tid = threadIdx.x;

    if (bid < PX_N) {
        // ---- x -> bf16 ----
        int idx = (bid*256 + tid)*8;
        float4 a = *(const float4*)&x[idx];
        float4 b = *(const float4*)&x[idx+4];
        uint4 o;
        o.x = cvtpk(a.x, a.y); o.y = cvtpk(a.z, a.w);
        o.z = cvtpk(b.x, b.y); o.w = cvtpk(b.z, b.w);
        *(uint4*)&xbf[idx] = o;
    } else if (bid < PWMIX_AT) {
        // ---- pack+transpose qkv weights -> wpackT [H][192][1024] ----
        ushort* T = (ushort*)psm;
        int i = bid - PX_N;
        int dt = i & 15, t = (i >> 4) % 3, h = (i >> 4) / 3;
        const float* w = (t == 0) ? wq : (t == 1) ? wk : wv;
        w += (size_t)h*Dv*DHv;
        int row = tid >> 2, c4 = tid & 3;
        #pragma unroll
        for (int q4 = 0; q4 < 4; ++q4) {
            float4 v = *(const float4*)&w[(size_t)(dt*64+row)*DHv + c4*16 + q4*4];
            T[(c4*16 + q4*4 + 0)*65 + row] = f2bf(v.x);
            T[(c4*16 + q4*4 + 1)*65 + row] = f2bf(v.y);
            T[(c4*16 + q4*4 + 2)*65 + row] = f2bf(v.z);
            T[(c4*16 + q4*4 + 3)*65 + row] = f2bf(v.w);
        }
        __syncthreads();
        #pragma unroll
        for (int i2 = 0; i2 < 2; ++i2) {
            int f = tid + i2*256;
            int e = f >> 3, c = f & 7;
            uint u[4];
            #pragma unroll
            for (int j = 0; j < 4; ++j) {
                uint lo = T[e*65 + c*8 + 2*j];
                uint hi = T[e*65 + c*8 + 2*j + 1];
                u[j] = lo | (hi << 16);
            }
            *(uint4*)&wpackT[((size_t)h*192 + t*64 + e)*Dv + dt*64 + c*8] = make_uint4(u[0],u[1],u[2],u[3]);
        }
    } else if (bid == PWMIX_AT) {
        // ---- w_mix -> transposed bf16 [e][f] ----
        int e = tid >> 2, f4 = tid & 3;
        #pragma unroll
        for (int j = 0; j < 16; ++j) {
            int f = f4*16 + j;
            wmixT[e*64 + f] = f2bf(wm[f*64 + e]);
        }
    } else if (bid < PBIAS_AT) {
        // ---- woTcat [1024 n][2432 k] = [w_o^T | (adj-folded w_o)^T] ----
        int j2 = bid - PWO2_AT;
        int nt = j2 & 15, g = j2 >> 4;
        int e = tid >> 2, n4 = tid & 3;
        float acc[16], part1[16];
        #pragma unroll
        for (int j = 0; j < 16; ++j) { acc[j] = 0.f; part1[j] = 0.f; }
        for (int h2 = 0; h2 < H; ++h2) {
            float a = adj[h2*H + g];
            const float* rp = wo + (size_t)(h2*64 + e)*Dv + nt*64 + n4*16;
            #pragma unroll
            for (int j4 = 0; j4 < 4; ++j4) {
                float4 v = *(const float4*)&rp[j4*4];
                acc[j4*4+0] += a*v.x; acc[j4*4+1] += a*v.y;
                acc[j4*4+2] += a*v.z; acc[j4*4+3] += a*v.w;
                if (h2 == g) {
                    part1[j4*4+0] = v.x; part1[j4*4+1] = v.y;
                    part1[j4*4+2] = v.z; part1[j4*4+3] = v.w;
                }
            }
        }
        #pragma unroll
        for (int j = 0; j < 16; ++j) {
            int n = nt*64 + n4*16 + j;
            woTcat[(size_t)n*KK2 + g*64 + e]         = f2bf(part1[j]);
            woTcat[(size_t)n*KK2 + H*DHv + g*64 + e] = f2bf(acc[j]);
        }
    } else {
        // ---- bias: relu(coords@wb1+bb1)@wb2+bb2, 4-way split d-loop ----
        float* part = (float*)psm;
        int hh = bid - PBIAS_AT;
        int e = tid & 63, quar = tid >> 6;
        float c0 = coords[hh*2], c1 = coords[hh*2+1];
        float acc = (quar == 0) ? bb2[e] : 0.f;
        int d0 = quar*256;
        for (int d = d0; d < d0+256; ++d) {
            float t2 = fmaxf(c0*wb1[d] + c1*wb1[Dv+d] + bb1[d], 0.f);
            acc += t2 * wb2[d*DHv + e];
        }
        if (quar) part[(quar-1)*64 + e] = acc;
        __syncthreads();
        if (quar == 0) bias[hh*DHv + e] = acc + part[e] + part[64+e] + part[128+e];
    }
}

// ---------------- QKV projection, bf16 MFMA ----------------
__global__ __launch_bounds__(256) void qkv_mfma(const ushort* __restrict__ xbf,
                                                const ushort* __restrict__ wpackT,
                                                const float* __restrict__ bias,
                                                ushort* __restrict__ qbf,
                                                ushort* __restrict__ kbf,
                                                ushort* __restrict__ vtbf) {
    const int mt = blockIdx.x, h = blockIdx.y;
    const int m0 = mt*64;
    const int tid = threadIdx.x;
    const int w = tid >> 6, lane = tid & 63;
    const int g = lane >> 4, r = lane & 15;

    __shared__ char lds[8192 + 24576];
    char* Xs = lds;
    char* Ws = lds + 8192;
    ushort* VtL = (ushort*)lds;

    f32x4 acc[4][3];
    const f32x4 zf = {0.f,0.f,0.f,0.f};
    #pragma unroll
    for (int m = 0; m < 4; ++m)
        #pragma unroll
        for (int n = 0; n < 3; ++n) acc[m][n] = zf;

    const ushort* xb = xbf + (size_t)m0*Dv;
    const ushort* wb = wpackT + (size_t)h*192*Dv;

    for (int kt = 0; kt < Dv; kt += 64) {
        __syncthreads();
        #pragma unroll
        for (int i = 0; i < 2; ++i) {
            int f = tid + i*256;
            int row = f >> 3, c = f & 7;
            *(bf16x8*)(Xs + row*128 + ((c*16) ^ ((row & 7) << 4))) =
                *(const bf16x8*)(xb + (size_t)row*Dv + kt + c*8);
        }
        #pragma unroll
        for (int i = 0; i < 6; ++i) {
            int f = tid + i*256;
            int row = f >> 3, c = f & 7;
            *(bf16x8*)(Ws + row*128 + ((c*16) ^ ((row & 7) << 4))) =
                *(const bf16x8*)(wb + (size_t)row*Dv + kt + c*8);
        }
        __syncthreads();
        #pragma unroll
        for (int kk = 0; kk < 2; ++kk) {
            bf16x8 a[4], bfr[3];
            #pragma unroll
            for (int m = 0; m < 4; ++m) {
                int row = m*16 + r;
                a[m] = *(const bf16x8*)(Xs + row*128 + (((kk*32 + g*8)*2) ^ ((row & 7) << 4)));
            }
            #pragma unroll
            for (int n = 0; n < 3; ++n) {
                int row = (w*3 + n)*16 + r;
                bfr[n] = *(const bf16x8*)(Ws + row*128 + (((kk*32 + g*8)*2) ^ ((row & 7) << 4)));
            }
            #pragma unroll
            for (int m = 0; m < 4; ++m)
                #pragma unroll
                for (int n = 0; n < 3; ++n)
                    acc[m][n] = __builtin_amdgcn_mfma_f32_16x16x32_bf16(a[m], bfr[n], acc[m][n], 0, 0, 0);
        }
    }

    __syncthreads();

    const int bb = m0 >> 11;
    const int s0 = m0 & 2047;
    #pragma unroll
    for (int m = 0; m < 4; ++m) {
        #pragma unroll
        for (int n = 0; n < 3; ++n) {
            int ng = w*3 + n;
            int t = ng >> 2;
            int e = (ng & 3)*16 + r;
            if (t == 0) {
                float bvv = bias[h*DHv + e];
                #pragma unroll
                for (int reg = 0; reg < 4; ++reg) {
                    int ss = s0 + m*16 + g*4 + reg;
                    qbf[(((size_t)bb*H + h)*Sv + ss)*DHv + e] = f2bf((acc[m][n][reg] + bvv)*QSCALE);
                }
            } else if (t == 1) {
                #pragma unroll
                for (int reg = 0; reg < 4; ++reg) {
                    int ss = s0 + m*16 + g*4 + reg;
                    kbf[(((size_t)bb*H + h)*Sv + ss)*DHv + e] = f2bf(acc[m][n][reg]);
                }
            } else {
                #pragma unroll
                for (int reg = 0; reg < 4; ++reg) {
                    int sl = m*16 + g*4 + reg;
                    VtL[e*66 + sl] = f2bf(acc[m][n][reg]);
                }
            }
        }
    }
    __syncthreads();
    #pragma unroll
    for (int i = 0; i < 2; ++i) {
        int f = tid + i*256;
        int dh = f >> 3, sc = f & 7;
        uint u[4];
        #pragma unroll
        for (int j = 0; j < 4; ++j) {
            uint lo = VtL[dh*66 + sc*8 + 2*j];
            uint hi = VtL[dh*66 + sc*8 + 2*j + 1];
            u[j] = lo | (hi << 16);
        }
        *(uint4*)&vtbf[(((size_t)bb*H + h)*DHv + dh)*Sv + s0 + sc*8] = make_uint4(u[0],u[1],u[2],u[3]);
    }
}

// ---------------- MFMA flash attention + fused GNN msg ----------------
// 64 q-rows/block, 4 waves x 16 q-rows. Double-buffered K/V staging with
// counted vmcnt + raw s_barrier (no __syncthreads drain). exp2-domain softmax
// (Q pre-scaled by 0.125*log2e). XCD-chunked block swizzle (1216 = 8*152).
__global__ __launch_bounds__(256) void attn_mfma(const ushort* __restrict__ qg,
                                                 const ushort* __restrict__ kg,
                                                 const ushort* __restrict__ vtg,
                                                 const ushort* __restrict__ wmixT,
                                                 ushort* __restrict__ headsbf,
                                                 ushort* __restrict__ msgbf) {
    const int hw = blockIdx.x;
    const int logical = (hw & 7) * 152 + (hw >> 3);   // 1216 = 8 XCD * 152
    const int qt = logical & 31;
    const int hb = logical >> 5;
    const int h = hb % H, b = hb / H;

    const int tid = threadIdx.x;
    const int w = tid >> 6, lane = tid & 63;
    const int g = lane >> 4, r = lane & 15;
    const int srow = lane >> 3, scl = lane & 7;

    __shared__ ushort Ks[2][4096];   // [kv 64][dh 64] swizzled
    __shared__ ushort Vs[2][4096];   // [dh 64][kv 64] swizzled
    __shared__ ushort Ps[4][1024];   // per-wave P / heads^T bounce

    const size_t bh = (size_t)b*H + h;
    const ushort* kb = kg + bh*Sv*DHv;
    const ushort* vb = vtg + bh*DHv*Sv;
    const ushort* qb = qg + (bh*Sv + qt*64 + w*16 + r)*DHv;

    bf16x8 qf0 = *(const bf16x8*)(qb + g*8);
    bf16x8 qf1 = *(const bf16x8*)(qb + 32 + g*8);

    float m_run = -1e30f, l_run = 0.f;
    f32x4 o[4];
    const f32x4 zf = {0.f,0.f,0.f,0.f};
    o[0]=zf; o[1]=zf; o[2]=zf; o[3]=zf;

    // per wave: 4 gll16 (2 K + 2 V) — linear LDS dest, inverse-swizzled source
    auto STAGE = [&](int jt_, int bi_) {
        #pragma unroll
        for (int is = 0; is < 2; ++is) {
            int row = w*16 + is*8 + srow;
            int kcol = (scl ^ (row & 7)) * 8;
            gll16(kb + (size_t)(jt_*64 + row)*DHv + kcol, &Ks[bi_][(w*16 + is*8)*64]);
            gll16(vb + (size_t)row*Sv + jt_*64 + kcol, &Vs[bi_][(w*16 + is*8)*64]);
        }
    };

    STAGE(0, 0);

    for (int jt = 0; jt < Sv/64; ++jt) {
        const int cur = jt & 1;
        if (jt < Sv/64 - 1) {
            STAGE(jt+1, cur^1);                              // prefetch next tile
            asm volatile("s_waitcnt vmcnt(4)" ::: "memory"); // tile jt landed
        } else {
            asm volatile("s_waitcnt vmcnt(0)" ::: "memory");
        }
        __builtin_amdgcn_sched_barrier(0);
        __builtin_amdgcn_s_barrier();                        // all waves' tile jt in LDS
        __builtin_amdgcn_sched_barrier(0);

        const ushort* Kc = Ks[cur];
        const ushort* Vc = Vs[cur];

        // scores SWAPPED: D[kv][q] = mfma(K, Q); lane holds q=r, kv = nt*16+g*4+reg
        f32x4 sc[4];
        sc[0]=zf; sc[1]=zf; sc[2]=zf; sc[3]=zf;
        #pragma unroll
        for (int kk = 0; kk < 2; ++kk) {
            bf16x8 qf = kk ? qf1 : qf0;
            #pragma unroll
            for (int nt = 0; nt < 4; ++nt) {
                int kvrow = nt*16 + r;
                bf16x8 kf = *(const bf16x8*)((const char*)Kc + kvrow*128 +
                                             ((kk*64 + g*16) ^ ((kvrow & 7) << 4)));
                sc[nt] = __builtin_amdgcn_mfma_f32_16x16x32_bf16(kf, qf, sc[nt], 0, 0, 0);
            }
        }

        // row-local softmax in exp2 domain
        float pmax = sc[0][0];
        #pragma unroll
        for (int nt = 0; nt < 4; ++nt)
            #pragma unroll
            for (int reg = 0; reg < 4; ++reg)
                pmax = fmaxf(pmax, sc[nt][reg]);
        pmax = fmaxf(pmax, __shfl_xor(pmax, 16));
        pmax = fmaxf(pmax, __shfl_xor(pmax, 32));

        if (__any(pmax > m_run + 8.0f)) {     // defer-max: P bounded by 2^8
            float mn = fmaxf(m_run, pmax);
            float corr = fexp2(m_run - mn);
            l_run *= corr;
            #pragma unroll
            for (int nt2 = 0; nt2 < 4; ++nt2) {
                o[nt2][0] *= corr; o[nt2][1] *= corr;
                o[nt2][2] *= corr; o[nt2][3] *= corr;
            }
            m_run = mn;
        }

        float lsum = 0.f;
        #pragma unroll
        for (int nt = 0; nt < 4; ++nt) {
            #pragma unroll
            for (int reg = 0; reg < 4; ++reg) {
                float p = fexp2(sc[nt][reg] - m_run);
                sc[nt][reg] = p;
                lsum += p;
            }
        }
        lsum += __shfl_xor(lsum, 16);
        lsum += __shfl_xor(lsum, 32);
        l_run += lsum;

        // pack P -> Ps[w] [q=r][kv], b64 writes, chunk-swizzled by q-row
        ushort* pw = Ps[w];
        #pragma unroll
        for (int nt = 0; nt < 4; ++nt) {
            uint u0 = cvtpk(sc[nt][0], sc[nt][1]);
            uint u1 = cvtpk(sc[nt][2], sc[nt][3]);
            int chunk = (2*nt + (g >> 1)) ^ (r & 7);
            *(uint2*)((char*)pw + r*128 + (chunk << 4) + ((g & 1)*8)) = make_uint2(u0, u1);
        }

        // PV SWAPPED: O^T[dh][q] += mfma(V^T, P)
        #pragma unroll
        for (int kk = 0; kk < 2; ++kk) {
            bf16x8 pa = *(const bf16x8*)((const char*)pw + r*128 +
                                         (((kk*4 + g) ^ (r & 7)) << 4));
            #pragma unroll
            for (int nt2 = 0; nt2 < 4; ++nt2) {
                int dh = nt2*16 + r;
                bf16x8 vf = *(const bf16x8*)((const char*)Vc + dh*128 +
                                             ((kk*64 + g*16) ^ ((dh & 7) << 4)));
                o[nt2] = __builtin_amdgcn_mfma_f32_16x16x32_bf16(vf, pa, o[nt2], 0, 0, 0);
            }
        }
        __builtin_amdgcn_sched_barrier(0);
        __builtin_amdgcn_s_barrier();     // reads of buf[cur] done before next overwrite
    }

    // epilogue: normalize, store heads bf16, stash heads^T in Ps for fused msg
    float inv = 1.0f / l_run;
    ushort* hp = headsbf + (bh*Sv + qt*64 + w*16 + r)*DHv;
    ushort* pw = Ps[w];
    #pragma unroll
    for (int nt2 = 0; nt2 < 4; ++nt2) {
        uint u0 = cvtpk(o[nt2][0]*inv, o[nt2][1]*inv);
        uint u1 = cvtpk(o[nt2][2]*inv, o[nt2][3]*inv);
        *(uint2*)(hp + nt2*16 + g*4) = make_uint2(u0, u1);
        int chunk = (2*nt2 + (g >> 1)) ^ (r & 7);
        *(uint2*)((char*)pw + r*128 + (chunk << 4) + ((g & 1)*8)) = make_uint2(u0, u1);
    }

    // fused msg = relu(heads @ w_mix): msg^T = mfma(w_mix^T, heads^T)
    bf16x8 wmf[2][4];
    #pragma unroll
    for (int kk = 0; kk < 2; ++kk)
        #pragma unroll
        for (int nt = 0; nt < 4; ++nt)
            wmf[kk][nt] = *(const bf16x8*)(wmixT + (nt*16 + r)*64 + kk*32 + g*8);

    f32x4 macc[4];
    macc[0]=zf; macc[1]=zf; macc[2]=zf; macc[3]=zf;
    #pragma unroll
    for (int kk = 0; kk < 2; ++kk) {
        bf16x8 pa = *(const bf16x8*)((const char*)pw + r*128 +
                                     (((kk*4 + g) ^ (r & 7)) << 4));
        #pragma unroll
        for (int nt = 0; nt < 4; ++nt)
            macc[nt] = __builtin_amdgcn_mfma_f32_16x16x32_bf16(wmf[kk][nt], pa, macc[nt], 0, 0, 0);
    }
    ushort* mp = msgbf + (bh*Sv + qt*64 + w*16 + r)*DHv;
    #pragma unroll
    for (int nt = 0; nt < 4; ++nt) {
        uint u0 = cvtpk(fmaxf(macc[nt][0], 0.f), fmaxf(macc[nt][1], 0.f));
        uint u1 = cvtpk(fmaxf(macc[nt][2], 0.f), fmaxf(macc[nt][3], 0.f));
        *(uint2*)(mp + nt*16 + g*4) = make_uint2(u0, u1);
    }
}

// ---------------- out projection: [heads|msg] (K=2432) @ woTcat -> out fp32 ----------------
__global__ __launch_bounds__(256) void out_mfma(const ushort* __restrict__ headsbf,
                                                const ushort* __restrict__ msgbf,
                                                const ushort* __restrict__ woTcat,
                                                float* __restrict__ out) {
    const int mt = blockIdx.x, nt2 = blockIdx.y;
    const int m0 = mt*64, n0 = nt2*128;
    const int tid = threadIdx.x;
    const int w = tid >> 6, lane = tid & 63;
    const int g = lane >> 4, r = lane & 15;

    __shared__ char lds[8192 + 16384];
    char* As = lds;
    char* Bs = lds + 8192;

    const int b = m0 >> 11;
    const int s0 = m0 & 2047;

    f32x4 acc[8];
    const f32x4 zf = {0.f,0.f,0.f,0.f};
    #pragma unroll
    for (int n = 0; n < 8; ++n) acc[n] = zf;

    for (int ktile = 0; ktile < KK2/64; ++ktile) {
        const int hh = (ktile < H) ? ktile : ktile - H;
        const ushort* asrc = ((ktile < H) ? headsbf : msgbf) +
                             ((size_t)((size_t)b*H + hh)*Sv + s0)*DHv;
        __syncthreads();
        #pragma unroll
        for (int i = 0; i < 2; ++i) {
            int f = tid + i*256;
            int row = f >> 3, c = f & 7;
            *(bf16x8*)(As + row*128 + ((c*16) ^ ((row & 7) << 4))) =
                *(const bf16x8*)(asrc + (size_t)row*DHv + c*8);
        }
        #pragma unroll
        for (int i = 0; i < 4; ++i) {
            int f = tid + i*256;
            int row = f >> 3, c = f & 7;
            *(bf16x8*)(Bs + row*128 + ((c*16) ^ ((row & 7) << 4))) =
                *(const bf16x8*)(woTcat + (size_t)(n0 + row)*KK2 + ktile*64 + c*8);
        }
        __syncthreads();
        #pragma unroll
        for (int kk = 0; kk < 2; ++kk) {
            int arow = w*16 + r;
            bf16x8 a = *(const bf16x8*)(As + arow*128 + (((kk*32 + g*8)*2) ^ ((arow & 7) << 4)));
            #pragma unroll
            for (int n = 0; n < 8; ++n) {
                int brow = n*16 + r;
                bf16x8 bfr = *(const bf16x8*)(Bs + brow*128 + (((kk*32 + g*8)*2) ^ ((brow & 7) << 4)));
                acc[n] = __builtin_amdgcn_mfma_f32_16x16x32_bf16(a, bfr, acc[n], 0, 0, 0);
            }
        }
    }

    #pragma unroll
    for (int n = 0; n < 8; ++n) {
        #pragma unroll
        for (int reg = 0; reg < 4; ++reg) {
            int grow = m0 + w*16 + g*4 + reg;
            out[(size_t)grow*Dv + n0 + n*16 + r] = acc[n][reg];
        }
    }
}

extern "C" void kernel_launch(void* const* d_in, const int* in_sizes, int n_in,
                              void* d_out, int out_size, void* d_ws, size_t ws_size,
                              hipStream_t stream) {
    const float* x      = (const float*)d_in[0];
    const float* coords = (const float*)d_in[1];
    const float* w_q    = (const float*)d_in[2];
    const float* w_k    = (const float*)d_in[3];
    const float* w_v    = (const float*)d_in[4];
    const float* wb1    = (const float*)d_in[5];
    const float* bb1    = (const float*)d_in[6];
    const float* wb2    = (const float*)d_in[7];
    const float* bb2    = (const float*)d_in[8];
    const float* w_mix  = (const float*)d_in[9];
    const float* adj    = (const float*)d_in[10];
    const float* w_o    = (const float*)d_in[11];

    char* ws = (char*)d_ws;
    const size_t QKV_BYTES = (size_t)Bv*H*Sv*DHv*2;   // 9,961,472
    const size_t XBF_BYTES = (size_t)Bv*Sv*Dv*2;      // 8,388,608
    const size_t WPK_BYTES = (size_t)H*192*Dv*2;      // 7,471,104

    size_t off = 0;
    float*  bias  = (float*)(ws + off);  off += 16384;
    ushort* qbf   = (ushort*)(ws + off); off += QKV_BYTES;
    ushort* kbf   = (ushort*)(ws + off); off += QKV_BYTES;
    ushort* vtbf  = (ushort*)(ws + off); off += QKV_BYTES;
    ushort* hdbf  = (ushort*)(ws + off); off += QKV_BYTES;
    ushort* xbf   = (ushort*)(ws + off);
    ushort* msgbf = xbf;                              // aliases xbf+wpkT (dead after qkv)
    off += XBF_BYTES;
    ushort* wpkT  = (ushort*)(ws + off); off += WPK_BYTES;
    ushort* wmixT = (ushort*)(ws + off); off += 8192;
    ushort* woTc  = (ushort*)(ws + off); off += (size_t)Dv*KK2*2;
    float*  out   = (float*)d_out;

    prep_all<<<PREP_N, 256, 0, stream>>>(x, w_q, w_k, w_v, w_o, adj, w_mix,
                                         coords, wb1, bb1, wb2, bb2,
                                         xbf, wpkT, wmixT, woTc, bias);
    qkv_mfma<<<dim3(64, H), 256, 0, stream>>>(xbf, wpkT, bias, qbf, kbf, vtbf);
    attn_mfma<<<1216, 256, 0, stream>>>(qbf, kbf, vtbf, wmixT, hdbf, msgbf);
    out_mfma<<<dim3(64, 8), 256, 0, stream>>>(hdbf, msgbf, woTc, out);
}

// Round 7
// 345.416 us; speedup vs baseline: 1.0756x; 1.0332x over previous
//
#include <hip/hip_runtime.h>
#include <hip/hip_bf16.h>

#define H 19
#define Bv 2
#define Sv 2048
#define Dv 1024
#define DHv 64
#define KK2 (2*H*DHv)   // 2432
// 0.125 * log2(e): scores come out of QK^T already in log2 domain
#define QSCALE 0.1803368801111204f

typedef __bf16 bf16x8 __attribute__((ext_vector_type(8)));
typedef float f32x4 __attribute__((ext_vector_type(4)));

__device__ __forceinline__ ushort f2bf(float f) {
    uint u = __float_as_uint(f);
    u = (u + 0x7fffu + ((u >> 16) & 1u)) >> 16;
    return (ushort)u;
}

__device__ __forceinline__ uint cvtpk(float lo, float hi) {
    uint r;
    asm("v_cvt_pk_bf16_f32 %0, %1, %2" : "=v"(r) : "v"(lo), "v"(hi));
    return r;
}

__device__ __forceinline__ float fexp2(float x) {
#if __has_builtin(__builtin_amdgcn_exp2f)
    return __builtin_amdgcn_exp2f(x);
#else
    return exp2f(x);
#endif
}

// async global->LDS, 16B per lane; dest = wave-uniform base + lane*16
__device__ __forceinline__ void gll16(const ushort* g, ushort* l) {
    __builtin_amdgcn_global_load_lds(
        (const __attribute__((address_space(1))) unsigned int*)g,
        (__attribute__((address_space(3))) unsigned int*)l, 16, 0, 0);
}

// ---------------- merged prep, LONG POLES FIRST ----------------
// order: bias(19) | wo2(304) | wmix(1) | wpack(912) | x-convert(2048)
#define PBIAS_AT 0
#define PWO2_AT  (PBIAS_AT + H)        // 19
#define PWMIX_AT (PWO2_AT + 304)       // 323
#define PWPK_AT  (PWMIX_AT + 1)        // 324
#define PX_AT    (PWPK_AT + 912)       // 1236
#define PREP_N   (PX_AT + 2048)        // 3284

__global__ __launch_bounds__(256) void prep_all(
    const float* __restrict__ x,  const float* __restrict__ wq,
    const float* __restrict__ wk, const float* __restrict__ wv,
    const float* __restrict__ wo, const float* __restrict__ adj,
    const float* __restrict__ wm, const float* __restrict__ coords,
    const float* __restrict__ wb1, const float* __restrict__ bb1,
    const float* __restrict__ wb2, const float* __restrict__ bb2,
    ushort* __restrict__ xbf, ushort* __restrict__ wpackT,
    ushort* __restrict__ wmixT, ushort* __restrict__ woTcat,
    float* __restrict__ bias)
{
    __shared__ char psm[18432];
    const int bid = blockIdx.x;
    const int tid = threadIdx.x;

    if (bid < PWO2_AT) {
        // ---- bias: relu(coords@wb1+bb1)@wb2+bb2, 4-way split d-loop ----
        float* part = (float*)psm;
        int hh = bid - PBIAS_AT;
        int e = tid & 63, quar = tid >> 6;
        float c0 = coords[hh*2], c1 = coords[hh*2+1];
        float acc = (quar == 0) ? bb2[e] : 0.f;
        int d0 = quar*256;
        for (int d = d0; d < d0+256; ++d) {
            float t2 = fmaxf(c0*wb1[d] + c1*wb1[Dv+d] + bb1[d], 0.f);
            acc += t2 * wb2[d*DHv + e];
        }
        if (quar) part[(quar-1)*64 + e] = acc;
        __syncthreads();
        if (quar == 0) bias[hh*DHv + e] = acc + part[e] + part[64+e] + part[128+e];
    } else if (bid < PWMIX_AT) {
        // ---- woTcat [1024 n][2432 k] = [w_o^T | (adj-folded w_o)^T] ----
        // coalesced reads; LDS transpose; coalesced 128B-row writes
        int j2 = bid - PWO2_AT;
        int nt = j2 & 15, g = j2 >> 4;
        int e = tid >> 2, n4 = tid & 3;
        float acc[16], part1[16];
        #pragma unroll
        for (int j = 0; j < 16; ++j) { acc[j] = 0.f; part1[j] = 0.f; }
        for (int h2 = 0; h2 < H; ++h2) {
            float a = adj[h2*H + g];
            const float* rp = wo + (size_t)(h2*64 + e)*Dv + nt*64 + n4*16;
            #pragma unroll
            for (int j4 = 0; j4 < 4; ++j4) {
                float4 v = *(const float4*)&rp[j4*4];
                acc[j4*4+0] += a*v.x; acc[j4*4+1] += a*v.y;
                acc[j4*4+2] += a*v.z; acc[j4*4+3] += a*v.w;
                if (h2 == g) {
                    part1[j4*4+0] = v.x; part1[j4*4+1] = v.y;
                    part1[j4*4+2] = v.z; part1[j4*4+3] = v.w;
                }
            }
        }
        ushort* T = (ushort*)psm;   // [2][64 n][72 e] (stride 72 -> 16B aligned rows)
        #pragma unroll
        for (int j = 0; j < 16; ++j) {
            int nl = n4*16 + j;
            T[nl*72 + e]         = f2bf(part1[j]);
            T[64*72 + nl*72 + e] = f2bf(acc[j]);
        }
        __syncthreads();
        int nl = tid >> 2, c = tid & 3;
        {
            ushort* dst = &woTcat[(size_t)(nt*64 + nl)*KK2 + g*64 + c*16];
            uint4 v0 = *(uint4*)&T[nl*72 + c*16];
            uint4 v1 = *(uint4*)&T[nl*72 + c*16 + 8];
            *(uint4*)dst = v0; *(uint4*)(dst + 8) = v1;
        }
        {
            ushort* dst = &woTcat[(size_t)(nt*64 + nl)*KK2 + H*DHv + g*64 + c*16];
            uint4 v0 = *(uint4*)&T[64*72 + nl*72 + c*16];
            uint4 v1 = *(uint4*)&T[64*72 + nl*72 + c*16 + 8];
            *(uint4*)dst = v0; *(uint4*)(dst + 8) = v1;
        }
    } else if (bid == PWMIX_AT) {
        // ---- w_mix -> transposed bf16 [e][f] ----
        int e = tid >> 2, f4 = tid & 3;
        #pragma unroll
        for (int j = 0; j < 16; ++j) {
            int f = f4*16 + j;
            wmixT[e*64 + f] = f2bf(wm[f*64 + e]);
        }
    } else if (bid < PX_AT) {
        // ---- pack+transpose qkv weights -> wpackT [H][192][1024] ----
        ushort* T = (ushort*)psm;
        int i = bid - PWPK_AT;
        int dt = i & 15, t = (i >> 4) % 3, h = (i >> 4) / 3;
        const float* w = (t == 0) ? wq : (t == 1) ? wk : wv;
        w += (size_t)h*Dv*DHv;
        int row = tid >> 2, c4 = tid & 3;
        #pragma unroll
        for (int q4 = 0; q4 < 4; ++q4) {
            float4 v = *(const float4*)&w[(size_t)(dt*64+row)*DHv + c4*16 + q4*4];
            T[(c4*16 + q4*4 + 0)*65 + row] = f2bf(v.x);
            T[(c4*16 + q4*4 + 1)*65 + row] = f2bf(v.y);
            T[(c4*16 + q4*4 + 2)*65 + row] = f2bf(v.z);
            T[(c4*16 + q4*4 + 3)*65 + row] = f2bf(v.w);
        }
        __syncthreads();
        #pragma unroll
        for (int i2 = 0; i2 < 2; ++i2) {
            int f = tid + i2*256;
            int e = f >> 3, c = f & 7;
            uint u[4];
            #pragma unroll
            for (int j = 0; j < 4; ++j) {
                uint lo = T[e*65 + c*8 + 2*j];
                uint hi = T[e*65 + c*8 + 2*j + 1];
                u[j] = lo | (hi << 16);
            }
            *(uint4*)&wpackT[((size_t)h*192 + t*64 + e)*Dv + dt*64 + c*8] = make_uint4(u[0],u[1],u[2],u[3]);
        }
    } else {
        // ---- x -> bf16 ----
        int idx = ((bid - PX_AT)*256 + tid)*8;
        float4 a = *(const float4*)&x[idx];
        float4 b = *(const float4*)&x[idx+4];
        uint4 o;
        o.x = cvtpk(a.x, a.y); o.y = cvtpk(a.z, a.w);
        o.z = cvtpk(b.x, b.y); o.w = cvtpk(b.z, b.w);
        *(uint4*)&xbf[idx] = o;
    }
}

// ---------------- QKV projection, bf16 MFMA ----------------
__global__ __launch_bounds__(256) void qkv_mfma(const ushort* __restrict__ xbf,
                                                const ushort* __restrict__ wpackT,
                                                const float* __restrict__ bias,
                                                ushort* __restrict__ qbf,
                                                ushort* __restrict__ kbf,
                                                ushort* __restrict__ vtbf) {
    const int mt = blockIdx.x, h = blockIdx.y;
    const int m0 = mt*64;
    const int tid = threadIdx.x;
    const int w = tid >> 6, lane = tid & 63;
    const int g = lane >> 4, r = lane & 15;

    __shared__ char lds[8192 + 24576];
    char* Xs = lds;
    char* Ws = lds + 8192;
    ushort* VtL = (ushort*)lds;

    f32x4 acc[4][3];
    const f32x4 zf = {0.f,0.f,0.f,0.f};
    #pragma unroll
    for (int m = 0; m < 4; ++m)
        #pragma unroll
        for (int n = 0; n < 3; ++n) acc[m][n] = zf;

    const ushort* xb = xbf + (size_t)m0*Dv;
    const ushort* wb = wpackT + (size_t)h*192*Dv;

    for (int kt = 0; kt < Dv; kt += 64) {
        __syncthreads();
        #pragma unroll
        for (int i = 0; i < 2; ++i) {
            int f = tid + i*256;
            int row = f >> 3, c = f & 7;
            *(bf16x8*)(Xs + row*128 + ((c*16) ^ ((row & 7) << 4))) =
                *(const bf16x8*)(xb + (size_t)row*Dv + kt + c*8);
        }
        #pragma unroll
        for (int i = 0; i < 6; ++i) {
            int f = tid + i*256;
            int row = f >> 3, c = f & 7;
            *(bf16x8*)(Ws + row*128 + ((c*16) ^ ((row & 7) << 4))) =
                *(const bf16x8*)(wb + (size_t)row*Dv + kt + c*8);
        }
        __syncthreads();
        #pragma unroll
        for (int kk = 0; kk < 2; ++kk) {
            bf16x8 a[4], bfr[3];
            #pragma unroll
            for (int m = 0; m < 4; ++m) {
                int row = m*16 + r;
                a[m] = *(const bf16x8*)(Xs + row*128 + (((kk*32 + g*8)*2) ^ ((row & 7) << 4)));
            }
            #pragma unroll
            for (int n = 0; n < 3; ++n) {
                int row = (w*3 + n)*16 + r;
                bfr[n] = *(const bf16x8*)(Ws + row*128 + (((kk*32 + g*8)*2) ^ ((row & 7) << 4)));
            }
            #pragma unroll
            for (int m = 0; m < 4; ++m)
                #pragma unroll
                for (int n = 0; n < 3; ++n)
                    acc[m][n] = __builtin_amdgcn_mfma_f32_16x16x32_bf16(a[m], bfr[n], acc[m][n], 0, 0, 0);
        }
    }

    __syncthreads();

    const int bb = m0 >> 11;
    const int s0 = m0 & 2047;
    #pragma unroll
    for (int m = 0; m < 4; ++m) {
        #pragma unroll
        for (int n = 0; n < 3; ++n) {
            int ng = w*3 + n;
            int t = ng >> 2;
            int e = (ng & 3)*16 + r;
            if (t == 0) {
                float bvv = bias[h*DHv + e];
                #pragma unroll
                for (int reg = 0; reg < 4; ++reg) {
                    int ss = s0 + m*16 + g*4 + reg;
                    qbf[(((size_t)bb*H + h)*Sv + ss)*DHv + e] = f2bf((acc[m][n][reg] + bvv)*QSCALE);
                }
            } else if (t == 1) {
                #pragma unroll
                for (int reg = 0; reg < 4; ++reg) {
                    int ss = s0 + m*16 + g*4 + reg;
                    kbf[(((size_t)bb*H + h)*Sv + ss)*DHv + e] = f2bf(acc[m][n][reg]);
                }
            } else {
                #pragma unroll
                for (int reg = 0; reg < 4; ++reg) {
                    int sl = m*16 + g*4 + reg;
                    VtL[e*66 + sl] = f2bf(acc[m][n][reg]);
                }
            }
        }
    }
    __syncthreads();
    #pragma unroll
    for (int i = 0; i < 2; ++i) {
        int f = tid + i*256;
        int dh = f >> 3, sc = f & 7;
        uint u[4];
        #pragma unroll
        for (int j = 0; j < 4; ++j) {
            uint lo = VtL[dh*66 + sc*8 + 2*j];
            uint hi = VtL[dh*66 + sc*8 + 2*j + 1];
            u[j] = lo | (hi << 16);
        }
        *(uint4*)&vtbf[(((size_t)bb*H + h)*DHv + dh)*Sv + s0 + sc*8] = make_uint4(u[0],u[1],u[2],u[3]);
    }
}

// ---------------- MFMA flash attention + fused GNN msg ----------------
// 64 q-rows/block, 4 waves x 16 q-rows. Single-buffer K/V staging (round-4
// structure: dbuf regressed via occupancy, m99/m100 pattern). exp2-domain
// softmax (Q pre-scaled 0.125*log2e). XCD-chunked swizzle (1216 = 8*152).
__global__ __launch_bounds__(256) void attn_mfma(const ushort* __restrict__ qg,
                                                 const ushort* __restrict__ kg,
                                                 const ushort* __restrict__ vtg,
                                                 const ushort* __restrict__ wmixT,
                                                 ushort* __restrict__ headsbf,
                                                 ushort* __restrict__ msgbf) {
    const int hw = blockIdx.x;
    const int logical = (hw & 7) * 152 + (hw >> 3);   // 1216 = 8 XCD * 152
    const int qt = logical & 31;
    const int hb = logical >> 5;
    const int h = hb % H, b = hb / H;

    const int tid = threadIdx.x;
    const int w = tid >> 6, lane = tid & 63;
    const int g = lane >> 4, r = lane & 15;
    const int srow = lane >> 3, scl = lane & 7;

    __shared__ ushort Ks[4096];      // [kv 64][dh 64] swizzled
    __shared__ ushort Vs[4096];      // [dh 64][kv 64] swizzled
    __shared__ ushort Ps[4][1024];   // per-wave P / heads^T bounce

    const size_t bh = (size_t)b*H + h;
    const ushort* kb = kg + bh*Sv*DHv;
    const ushort* vb = vtg + bh*DHv*Sv;
    const ushort* qb = qg + (bh*Sv + qt*64 + w*16 + r)*DHv;

    bf16x8 qf0 = *(const bf16x8*)(qb + g*8);
    bf16x8 qf1 = *(const bf16x8*)(qb + 32 + g*8);

    float m_run = -1e30f, l_run = 0.f;
    f32x4 o[4];
    const f32x4 zf = {0.f,0.f,0.f,0.f};
    o[0]=zf; o[1]=zf; o[2]=zf; o[3]=zf;

    for (int jt = 0; jt < Sv/64; ++jt) {
        __syncthreads();   // previous tile's reads complete before overwrite
        // stage K [64 kv][64 dh] and V^T [64 dh][64 kv]: linear LDS dest,
        // inverse-swizzled global source (rule #21)
        #pragma unroll
        for (int is = 0; is < 2; ++is) {
            int row = w*16 + is*8 + srow;
            int kcol = (scl ^ (row & 7)) * 8;
            gll16(kb + (size_t)(jt*64 + row)*DHv + kcol, &Ks[(w*16 + is*8)*64]);
            gll16(vb + (size_t)row*Sv + jt*64 + kcol, &Vs[(w*16 + is*8)*64]);
        }
        asm volatile("s_waitcnt vmcnt(0)" ::: "memory");
        __syncthreads();

        // scores SWAPPED: D[kv][q] = mfma(K, Q); lane holds q=r, kv = nt*16+g*4+reg
        f32x4 sc[4];
        sc[0]=zf; sc[1]=zf; sc[2]=zf; sc[3]=zf;
        #pragma unroll
        for (int kk = 0; kk < 2; ++kk) {
            bf16x8 qf = kk ? qf1 : qf0;
            #pragma unroll
            for (int nt = 0; nt < 4; ++nt) {
                int kvrow = nt*16 + r;
                bf16x8 kf = *(const bf16x8*)((const char*)Ks + kvrow*128 +
                                             ((kk*64 + g*16) ^ ((kvrow & 7) << 4)));
                sc[nt] = __builtin_amdgcn_mfma_f32_16x16x32_bf16(kf, qf, sc[nt], 0, 0, 0);
            }
        }

        // row-local softmax in exp2 domain
        float pmax = sc[0][0];
        #pragma unroll
        for (int nt = 0; nt < 4; ++nt)
            #pragma unroll
            for (int reg = 0; reg < 4; ++reg)
                pmax = fmaxf(pmax, sc[nt][reg]);
        pmax = fmaxf(pmax, __shfl_xor(pmax, 16));
        pmax = fmaxf(pmax, __shfl_xor(pmax, 32));

        if (__any(pmax > m_run + 8.0f)) {     // defer-max: P bounded by 2^8
            float mn = fmaxf(m_run, pmax);
            float corr = fexp2(m_run - mn);
            l_run *= corr;
            #pragma unroll
            for (int nt2 = 0; nt2 < 4; ++nt2) {
                o[nt2][0] *= corr; o[nt2][1] *= corr;
                o[nt2][2] *= corr; o[nt2][3] *= corr;
            }
            m_run = mn;
        }

        float lsum = 0.f;
        #pragma unroll
        for (int nt = 0; nt < 4; ++nt) {
            #pragma unroll
            for (int reg = 0; reg < 4; ++reg) {
                float p = fexp2(sc[nt][reg] - m_run);
                sc[nt][reg] = p;
                lsum += p;
            }
        }
        lsum += __shfl_xor(lsum, 16);
        lsum += __shfl_xor(lsum, 32);
        l_run += lsum;

        // pack P -> Ps[w] [q=r][kv], b64 writes, chunk-swizzled by q-row
        ushort* pw = Ps[w];
        #pragma unroll
        for (int nt = 0; nt < 4; ++nt) {
            uint u0 = cvtpk(sc[nt][0], sc[nt][1]);
            uint u1 = cvtpk(sc[nt][2], sc[nt][3]);
            int chunk = (2*nt + (g >> 1)) ^ (r & 7);
            *(uint2*)((char*)pw + r*128 + (chunk << 4) + ((g & 1)*8)) = make_uint2(u0, u1);
        }

        // PV SWAPPED: O^T[dh][q] += mfma(V^T, P)
        #pragma unroll
        for (int kk = 0; kk < 2; ++kk) {
            bf16x8 pa = *(const bf16x8*)((const char*)pw + r*128 +
                                         (((kk*4 + g) ^ (r & 7)) << 4));
            #pragma unroll
            for (int nt2 = 0; nt2 < 4; ++nt2) {
                int dh = nt2*16 + r;
                bf16x8 vf = *(const bf16x8*)((const char*)Vs + dh*128 +
                                             ((kk*64 + g*16) ^ ((dh & 7) << 4)));
                o[nt2] = __builtin_amdgcn_mfma_f32_16x16x32_bf16(vf, pa, o[nt2], 0, 0, 0);
            }
        }
    }

    // epilogue: normalize, store heads bf16, stash heads^T in Ps for fused msg
    float inv = 1.0f / l_run;
    ushort* hp = headsbf + (bh*Sv + qt*64 + w*16 + r)*DHv;
    ushort* pw = Ps[w];
    #pragma unroll
    for (int nt2 = 0; nt2 < 4; ++nt2) {
        uint u0 = cvtpk(o[nt2][0]*inv, o[nt2][1]*inv);
        uint u1 = cvtpk(o[nt2][2]*inv, o[nt2][3]*inv);
        *(uint2*)(hp + nt2*16 + g*4) = make_uint2(u0, u1);
        int chunk = (2*nt2 + (g >> 1)) ^ (r & 7);
        *(uint2*)((char*)pw + r*128 + (chunk << 4) + ((g & 1)*8)) = make_uint2(u0, u1);
    }

    // fused msg = relu(heads @ w_mix): msg^T = mfma(w_mix^T, heads^T)
    bf16x8 wmf[2][4];
    #pragma unroll
    for (int kk = 0; kk < 2; ++kk)
        #pragma unroll
        for (int nt = 0; nt < 4; ++nt)
            wmf[kk][nt] = *(const bf16x8*)(wmixT + (nt*16 + r)*64 + kk*32 + g*8);

    f32x4 macc[4];
    macc[0]=zf; macc[1]=zf; macc[2]=zf; macc[3]=zf;
    #pragma unroll
    for (int kk = 0; kk < 2; ++kk) {
        bf16x8 pa = *(const bf16x8*)((const char*)pw + r*128 +
                                     (((kk*4 + g) ^ (r & 7)) << 4));
        #pragma unroll
        for (int nt = 0; nt < 4; ++nt)
            macc[nt] = __builtin_amdgcn_mfma_f32_16x16x32_bf16(wmf[kk][nt], pa, macc[nt], 0, 0, 0);
    }
    ushort* mp = msgbf + (bh*Sv + qt*64 + w*16 + r)*DHv;
    #pragma unroll
    for (int nt = 0; nt < 4; ++nt) {
        uint u0 = cvtpk(fmaxf(macc[nt][0], 0.f), fmaxf(macc[nt][1], 0.f));
        uint u1 = cvtpk(fmaxf(macc[nt][2], 0.f), fmaxf(macc[nt][3], 0.f));
        *(uint2*)(mp + nt*16 + g*4) = make_uint2(u0, u1);
    }
}

// ---------------- out projection: [heads|msg] (K=2432) @ woTcat -> out fp32 ----------------
__global__ __launch_bounds__(256) void out_mfma(const ushort* __restrict__ headsbf,
                                                const ushort* __restrict__ msgbf,
                                                const ushort* __restrict__ woTcat,
                                                float* __restrict__ out) {
    const int mt = blockIdx.x, nt2 = blockIdx.y;
    const int m0 = mt*64, n0 = nt2*128;
    const int tid = threadIdx.x;
    const int w = tid >> 6, lane = tid & 63;
    const int g = lane >> 4, r = lane & 15;

    __shared__ char lds[8192 + 16384];
    char* As = lds;
    char* Bs = lds + 8192;

    const int b = m0 >> 11;
    const int s0 = m0 & 2047;

    f32x4 acc[8];
    const f32x4 zf = {0.f,0.f,0.f,0.f};
    #pragma unroll
    for (int n = 0; n < 8; ++n) acc[n] = zf;

    for (int ktile = 0; ktile < KK2/64; ++ktile) {
        const int hh = (ktile < H) ? ktile : ktile - H;
        const ushort* asrc = ((ktile < H) ? headsbf : msgbf) +
                             ((size_t)((size_t)b*H + hh)*Sv + s0)*DHv;
        __syncthreads();
        #pragma unroll
        for (int i = 0; i < 2; ++i) {
            int f = tid + i*256;
            int row = f >> 3, c = f & 7;
            *(bf16x8*)(As + row*128 + ((c*16) ^ ((row & 7) << 4))) =
                *(const bf16x8*)(asrc + (size_t)row*DHv + c*8);
        }
        #pragma unroll
        for (int i = 0; i < 4; ++i) {
            int f = tid + i*256;
            int row = f >> 3, c = f & 7;
            *(bf16x8*)(Bs + row*128 + ((c*16) ^ ((row & 7) << 4))) =
                *(const bf16x8*)(woTcat + (size_t)(n0 + row)*KK2 + ktile*64 + c*8);
        }
        __syncthreads();
        #pragma unroll
        for (int kk = 0; kk < 2; ++kk) {
            int arow = w*16 + r;
            bf16x8 a = *(const bf16x8*)(As + arow*128 + (((kk*32 + g*8)*2) ^ ((arow & 7) << 4)));
            #pragma unroll
            for (int n = 0; n < 8; ++n) {
                int brow = n*16 + r;
                bf16x8 bfr = *(const bf16x8*)(Bs + brow*128 + (((kk*32 + g*8)*2) ^ ((brow & 7) << 4)));
                acc[n] = __builtin_amdgcn_mfma_f32_16x16x32_bf16(a, bfr, acc[n], 0, 0, 0);
            }
        }
    }

    #pragma unroll
    for (int n = 0; n < 8; ++n) {
        #pragma unroll
        for (int reg = 0; reg < 4; ++reg) {
            int grow = m0 + w*16 + g*4 + reg;
            out[(size_t)grow*Dv + n0 + n*16 + r] = acc[n][reg];
        }
    }
}

extern "C" void kernel_launch(void* const* d_in, const int* in_sizes, int n_in,
                              void* d_out, int out_size, void* d_ws, size_t ws_size,
                              hipStream_t stream) {
    const float* x      = (const float*)d_in[0];
    const float* coords = (const float*)d_in[1];
    const float* w_q    = (const float*)d_in[2];
    const float* w_k    = (const float*)d_in[3];
    const float* w_v    = (const float*)d_in[4];
    const float* wb1    = (const float*)d_in[5];
    const float* bb1    = (const float*)d_in[6];
    const float* wb2    = (const float*)d_in[7];
    const float* bb2    = (const float*)d_in[8];
    const float* w_mix  = (const float*)d_in[9];
    const float* adj    = (const float*)d_in[10];
    const float* w_o    = (const float*)d_in[11];

    char* ws = (char*)d_ws;
    const size_t QKV_BYTES = (size_t)Bv*H*Sv*DHv*2;   // 9,961,472
    const size_t XBF_BYTES = (size_t)Bv*Sv*Dv*2;      // 8,388,608
    const size_t WPK_BYTES = (size_t)H*192*Dv*2;      // 7,471,104

    size_t off = 0;
    float*  bias  = (float*)(ws + off);  off += 16384;
    ushort* qbf   = (ushort*)(ws + off); off += QKV_BYTES;
    ushort* kbf   = (ushort*)(ws + off); off += QKV_BYTES;
    ushort* vtbf  = (ushort*)(ws + off); off += QKV_BYTES;
    ushort* hdbf  = (ushort*)(ws + off); off += QKV_BYTES;
    ushort* xbf   = (ushort*)(ws + off);
    ushort* msgbf = xbf;                              // aliases xbf+wpkT (dead after qkv)
    off += XBF_BYTES;
    ushort* wpkT  = (ushort*)(ws + off); off += WPK_BYTES;
    ushort* wmixT = (ushort*)(ws + off); off += 8192;
    ushort* woTc  = (ushort*)(ws + off); off += (size_t)Dv*KK2*2;
    float*  out   = (float*)d_out;

    prep_all<<<PREP_N, 256, 0, stream>>>(x, w_q, w_k, w_v, w_o, adj, w_mix,
                                         coords, wb1, bb1, wb2, bb2,
                                         xbf, wpkT, wmixT, woTc, bias);
    qkv_mfma<<<dim3(64, H), 256, 0, stream>>>(xbf, wpkT, bias, qbf, kbf, vtbf);
    attn_mfma<<<1216, 256, 0, stream>>>(qbf, kbf, vtbf, wmixT, hdbf, msgbf);
    out_mfma<<<dim3(64, 8), 256, 0, stream>>>(hdbf, msgbf, woTc, out);
}

// Round 8
// 315.560 us; speedup vs baseline: 1.1773x; 1.0946x over previous
//
#include <hip/hip_runtime.h>
#include <hip/hip_bf16.h>

#define H 19
#define Bv 2
#define Sv 2048
#define Dv 1024
#define DHv 64
#define KK2 (2*H*DHv)   // 2432
// 0.125 * log2(e): scores come out of QK^T already in log2 domain
#define QSCALE 0.1803368801111204f

typedef __bf16 bf16x8 __attribute__((ext_vector_type(8)));
typedef float f32x4 __attribute__((ext_vector_type(4)));

__device__ __forceinline__ ushort f2bf(float f) {
    uint u = __float_as_uint(f);
    u = (u + 0x7fffu + ((u >> 16) & 1u)) >> 16;
    return (ushort)u;
}

__device__ __forceinline__ uint cvtpk(float lo, float hi) {
    uint r;
    asm("v_cvt_pk_bf16_f32 %0, %1, %2" : "=v"(r) : "v"(lo), "v"(hi));
    return r;
}

__device__ __forceinline__ float fexp2(float x) {
#if __has_builtin(__builtin_amdgcn_exp2f)
    return __builtin_amdgcn_exp2f(x);
#else
    return exp2f(x);
#endif
}

// async global->LDS, 16B per lane; dest = wave-uniform base + lane*16
__device__ __forceinline__ void gll16(const ushort* g, ushort* l) {
    __builtin_amdgcn_global_load_lds(
        (const __attribute__((address_space(1))) unsigned int*)g,
        (__attribute__((address_space(3))) unsigned int*)l, 16, 0, 0);
}

// ---------------- prep_misc: wo2(304) | wpack(912) | wmix(1) | x(2048) ----------------
#define PWO2_AT  0
#define PWPK_AT  (PWO2_AT + 304)       // 304
#define PWMIX_AT (PWPK_AT + 912)       // 1216
#define PX_AT    (PWMIX_AT + 1)        // 1217
#define PREP_N   (PX_AT + 2048)        // 3265

__global__ __launch_bounds__(256) void prep_misc(
    const float* __restrict__ x,  const float* __restrict__ wq,
    const float* __restrict__ wk, const float* __restrict__ wv,
    const float* __restrict__ wo, const float* __restrict__ adj,
    const float* __restrict__ wm,
    ushort* __restrict__ xbf, ushort* __restrict__ wpackT,
    ushort* __restrict__ wmixT, ushort* __restrict__ woTcat)
{
    __shared__ char psm[18432];
    const int bid = blockIdx.x;
    const int tid = threadIdx.x;

    if (bid < PWPK_AT) {
        // ---- woTcat [1024 n][2432 k] = [w_o^T | (adj-folded w_o)^T] ----
        int j2 = bid - PWO2_AT;
        int nt = j2 & 15, g = j2 >> 4;
        int e = tid >> 2, n4 = tid & 3;
        float acc[16], part1[16];
        #pragma unroll
        for (int j = 0; j < 16; ++j) { acc[j] = 0.f; part1[j] = 0.f; }
        for (int h2 = 0; h2 < H; ++h2) {
            float a = adj[h2*H + g];
            const float* rp = wo + (size_t)(h2*64 + e)*Dv + nt*64 + n4*16;
            #pragma unroll
            for (int j4 = 0; j4 < 4; ++j4) {
                float4 v = *(const float4*)&rp[j4*4];
                acc[j4*4+0] += a*v.x; acc[j4*4+1] += a*v.y;
                acc[j4*4+2] += a*v.z; acc[j4*4+3] += a*v.w;
                if (h2 == g) {
                    part1[j4*4+0] = v.x; part1[j4*4+1] = v.y;
                    part1[j4*4+2] = v.z; part1[j4*4+3] = v.w;
                }
            }
        }
        ushort* T = (ushort*)psm;   // [2][64 n][72 e]
        #pragma unroll
        for (int j = 0; j < 16; ++j) {
            int nl = n4*16 + j;
            T[nl*72 + e]         = f2bf(part1[j]);
            T[64*72 + nl*72 + e] = f2bf(acc[j]);
        }
        __syncthreads();
        int nl = tid >> 2, c = tid & 3;
        {
            ushort* dst = &woTcat[(size_t)(nt*64 + nl)*KK2 + g*64 + c*16];
            uint4 v0 = *(uint4*)&T[nl*72 + c*16];
            uint4 v1 = *(uint4*)&T[nl*72 + c*16 + 8];
            *(uint4*)dst = v0; *(uint4*)(dst + 8) = v1;
        }
        {
            ushort* dst = &woTcat[(size_t)(nt*64 + nl)*KK2 + H*DHv + g*64 + c*16];
            uint4 v0 = *(uint4*)&T[64*72 + nl*72 + c*16];
            uint4 v1 = *(uint4*)&T[64*72 + nl*72 + c*16 + 8];
            *(uint4*)dst = v0; *(uint4*)(dst + 8) = v1;
        }
    } else if (bid < PWMIX_AT) {
        // ---- pack+transpose qkv weights -> wpackT [H][192][1024] ----
        ushort* T = (ushort*)psm;
        int i = bid - PWPK_AT;
        int dt = i & 15, t = (i >> 4) % 3, h = (i >> 4) / 3;
        const float* w = (t == 0) ? wq : (t == 1) ? wk : wv;
        w += (size_t)h*Dv*DHv;
        int row = tid >> 2, c4 = tid & 3;
        #pragma unroll
        for (int q4 = 0; q4 < 4; ++q4) {
            float4 v = *(const float4*)&w[(size_t)(dt*64+row)*DHv + c4*16 + q4*4];
            T[(c4*16 + q4*4 + 0)*65 + row] = f2bf(v.x);
            T[(c4*16 + q4*4 + 1)*65 + row] = f2bf(v.y);
            T[(c4*16 + q4*4 + 2)*65 + row] = f2bf(v.z);
            T[(c4*16 + q4*4 + 3)*65 + row] = f2bf(v.w);
        }
        __syncthreads();
        #pragma unroll
        for (int i2 = 0; i2 < 2; ++i2) {
            int f = tid + i2*256;
            int e = f >> 3, c = f & 7;
            uint u[4];
            #pragma unroll
            for (int j = 0; j < 4; ++j) {
                uint lo = T[e*65 + c*8 + 2*j];
                uint hi = T[e*65 + c*8 + 2*j + 1];
                u[j] = lo | (hi << 16);
            }
            *(uint4*)&wpackT[((size_t)h*192 + t*64 + e)*Dv + dt*64 + c*8] = make_uint4(u[0],u[1],u[2],u[3]);
        }
    } else if (bid == PWMIX_AT) {
        // ---- w_mix -> transposed bf16 [e][f] ----
        int e = tid >> 2, f4 = tid & 3;
        #pragma unroll
        for (int j = 0; j < 16; ++j) {
            int f = f4*16 + j;
            wmixT[e*64 + f] = f2bf(wm[f*64 + e]);
        }
    } else {
        // ---- x -> bf16 ----
        int idx = ((bid - PX_AT)*256 + tid)*8;
        float4 a = *(const float4*)&x[idx];
        float4 b = *(const float4*)&x[idx+4];
        uint4 o;
        o.x = cvtpk(a.x, a.y); o.y = cvtpk(a.z, a.w);
        o.z = cvtpk(b.x, b.y); o.w = cvtpk(b.z, b.w);
        *(uint4*)&xbf[idx] = o;
    }
}

// ---------------- bias partials: relu(coords@wb1+bb1)@wb2 (+bb2 in part 0) ----------------
// grid (4, H): block (bq,h) covers d in [bq*256, bq*256+256); 4 sub-quars of 64 d each.
// Writes bias_part[bq][h][64]; qkv epilogue sums the 4 partials.
__global__ __launch_bounds__(256) void bias_part_kernel(
    const float* __restrict__ coords, const float* __restrict__ wb1,
    const float* __restrict__ bb1, const float* __restrict__ wb2,
    const float* __restrict__ bb2, float* __restrict__ bias_part) {
    const int bq = blockIdx.x, hh = blockIdx.y;
    const int e = threadIdx.x & 63, sub = threadIdx.x >> 6;
    __shared__ float part[3][64];
    float c0 = coords[hh*2], c1 = coords[hh*2+1];
    float acc = (bq == 0 && sub == 0) ? bb2[e] : 0.f;
    const int d0 = bq*256 + sub*64;
    #pragma unroll 8
    for (int i = 0; i < 64; ++i) {
        int d = d0 + i;
        float t2 = fmaxf(c0*wb1[d] + c1*wb1[Dv+d] + bb1[d], 0.f);
        acc += t2 * wb2[d*DHv + e];
    }
    if (sub) part[sub-1][e] = acc;
    __syncthreads();
    if (sub == 0)
        bias_part[(bq*H + hh)*DHv + e] = acc + part[0][e] + part[1][e] + part[2][e];
}

// ---------------- QKV projection, bf16 MFMA ----------------
__global__ __launch_bounds__(256) void qkv_mfma(const ushort* __restrict__ xbf,
                                                const ushort* __restrict__ wpackT,
                                                const float* __restrict__ bias_part,
                                                ushort* __restrict__ qbf,
                                                ushort* __restrict__ kbf,
                                                ushort* __restrict__ vtbf) {
    const int mt = blockIdx.x, h = blockIdx.y;
    const int m0 = mt*64;
    const int tid = threadIdx.x;
    const int w = tid >> 6, lane = tid & 63;
    const int g = lane >> 4, r = lane & 15;

    __shared__ char lds[8192 + 24576];
    char* Xs = lds;
    char* Ws = lds + 8192;
    ushort* VtL = (ushort*)lds;

    f32x4 acc[4][3];
    const f32x4 zf = {0.f,0.f,0.f,0.f};
    #pragma unroll
    for (int m = 0; m < 4; ++m)
        #pragma unroll
        for (int n = 0; n < 3; ++n) acc[m][n] = zf;

    const ushort* xb = xbf + (size_t)m0*Dv;
    const ushort* wb = wpackT + (size_t)h*192*Dv;

    for (int kt = 0; kt < Dv; kt += 64) {
        __syncthreads();
        #pragma unroll
        for (int i = 0; i < 2; ++i) {
            int f = tid + i*256;
            int row = f >> 3, c = f & 7;
            *(bf16x8*)(Xs + row*128 + ((c*16) ^ ((row & 7) << 4))) =
                *(const bf16x8*)(xb + (size_t)row*Dv + kt + c*8);
        }
        #pragma unroll
        for (int i = 0; i < 6; ++i) {
            int f = tid + i*256;
            int row = f >> 3, c = f & 7;
            *(bf16x8*)(Ws + row*128 + ((c*16) ^ ((row & 7) << 4))) =
                *(const bf16x8*)(wb + (size_t)row*Dv + kt + c*8);
        }
        __syncthreads();
        #pragma unroll
        for (int kk = 0; kk < 2; ++kk) {
            bf16x8 a[4], bfr[3];
            #pragma unroll
            for (int m = 0; m < 4; ++m) {
                int row = m*16 + r;
                a[m] = *(const bf16x8*)(Xs + row*128 + (((kk*32 + g*8)*2) ^ ((row & 7) << 4)));
            }
            #pragma unroll
            for (int n = 0; n < 3; ++n) {
                int row = (w*3 + n)*16 + r;
                bfr[n] = *(const bf16x8*)(Ws + row*128 + (((kk*32 + g*8)*2) ^ ((row & 7) << 4)));
            }
            #pragma unroll
            for (int m = 0; m < 4; ++m)
                #pragma unroll
                for (int n = 0; n < 3; ++n)
                    acc[m][n] = __builtin_amdgcn_mfma_f32_16x16x32_bf16(a[m], bfr[n], acc[m][n], 0, 0, 0);
        }
    }

    __syncthreads();

    const int bb = m0 >> 11;
    const int s0 = m0 & 2047;
    #pragma unroll
    for (int m = 0; m < 4; ++m) {
        #pragma unroll
        for (int n = 0; n < 3; ++n) {
            int ng = w*3 + n;
            int t = ng >> 2;
            int e = (ng & 3)*16 + r;
            if (t == 0) {
                float bvv = bias_part[(0*H + h)*DHv + e] + bias_part[(1*H + h)*DHv + e]
                          + bias_part[(2*H + h)*DHv + e] + bias_part[(3*H + h)*DHv + e];
                #pragma unroll
                for (int reg = 0; reg < 4; ++reg) {
                    int ss = s0 + m*16 + g*4 + reg;
                    qbf[(((size_t)bb*H + h)*Sv + ss)*DHv + e] = f2bf((acc[m][n][reg] + bvv)*QSCALE);
                }
            } else if (t == 1) {
                #pragma unroll
                for (int reg = 0; reg < 4; ++reg) {
                    int ss = s0 + m*16 + g*4 + reg;
                    kbf[(((size_t)bb*H + h)*Sv + ss)*DHv + e] = f2bf(acc[m][n][reg]);
                }
            } else {
                #pragma unroll
                for (int reg = 0; reg < 4; ++reg) {
                    int sl = m*16 + g*4 + reg;
                    VtL[e*66 + sl] = f2bf(acc[m][n][reg]);
                }
            }
        }
    }
    __syncthreads();
    #pragma unroll
    for (int i = 0; i < 2; ++i) {
        int f = tid + i*256;
        int dh = f >> 3, sc = f & 7;
        uint u[4];
        #pragma unroll
        for (int j = 0; j < 4; ++j) {
            uint lo = VtL[dh*66 + sc*8 + 2*j];
            uint hi = VtL[dh*66 + sc*8 + 2*j + 1];
            u[j] = lo | (hi << 16);
        }
        *(uint4*)&vtbf[(((size_t)bb*H + h)*DHv + dh)*Sv + s0 + sc*8] = make_uint4(u[0],u[1],u[2],u[3]);
    }
}

// ---------------- MFMA flash attention + fused GNN msg, 2 waves x 32 q-rows ----------------
// 64 q-rows/block, 2 waves, each wave 2 q-groups of 16. K/V fragments loaded
// once per wave and reused across both groups (halves LDS-read per q-row).
// exp2-domain softmax (Q pre-scaled 0.125*log2e). XCD swizzle (1216 = 8*152).
__global__ __launch_bounds__(128) void attn_mfma(const ushort* __restrict__ qg,
                                                 const ushort* __restrict__ kg,
                                                 const ushort* __restrict__ vtg,
                                                 const ushort* __restrict__ wmixT,
                                                 ushort* __restrict__ headsbf,
                                                 ushort* __restrict__ msgbf) {
    const int hw = blockIdx.x;
    const int logical = (hw & 7) * 152 + (hw >> 3);   // 1216 = 8 XCD * 152
    const int qt = logical & 31;
    const int hb = logical >> 5;
    const int h = hb % H, b = hb / H;

    const int tid = threadIdx.x;
    const int w = tid >> 6, lane = tid & 63;
    const int g = lane >> 4, r = lane & 15;
    const int srow = lane >> 3, scl = lane & 7;

    __shared__ ushort Ks[4096];      // [kv 64][dh 64] swizzled
    __shared__ ushort Vs[4096];      // [dh 64][kv 64] swizzled
    __shared__ ushort Ps[2][1024];   // per-wave P / heads^T bounce (reused per group)

    const size_t bh = (size_t)b*H + h;
    const ushort* kb = kg + bh*Sv*DHv;
    const ushort* vb = vtg + bh*DHv*Sv;

    // Q fragments: [grp][kk]; wave w owns q rows qt*64 + w*32 + grp*16 + r
    bf16x8 qf[2][2];
    #pragma unroll
    for (int grp = 0; grp < 2; ++grp) {
        const ushort* qb = qg + (bh*Sv + qt*64 + w*32 + grp*16 + r)*DHv;
        qf[grp][0] = *(const bf16x8*)(qb + g*8);
        qf[grp][1] = *(const bf16x8*)(qb + 32 + g*8);
    }

    float m_run[2] = {-1e30f, -1e30f}, l_run[2] = {0.f, 0.f};
    f32x4 o[2][4];
    const f32x4 zf = {0.f,0.f,0.f,0.f};
    #pragma unroll
    for (int grp = 0; grp < 2; ++grp)
        #pragma unroll
        for (int n = 0; n < 4; ++n) o[grp][n] = zf;

    for (int jt = 0; jt < Sv/64; ++jt) {
        __syncthreads();   // previous tile's reads complete before overwrite
        // stage K [64 kv][64 dh] and V^T [64 dh][64 kv]: linear LDS dest,
        // inverse-swizzled global source (rule #21); 8 rows per gll16
        #pragma unroll
        for (int is = 0; is < 4; ++is) {
            int row = w*32 + is*8 + srow;
            int kcol = (scl ^ srow) * 8;
            gll16(kb + (size_t)(jt*64 + row)*DHv + kcol, &Ks[(w*32 + is*8)*64]);
            gll16(vb + (size_t)row*Sv + jt*64 + kcol, &Vs[(w*32 + is*8)*64]);
        }
        asm volatile("s_waitcnt vmcnt(0)" ::: "memory");
        __syncthreads();

        // K fragments once per wave, shared by both q-groups
        bf16x8 fr[2][4];
        #pragma unroll
        for (int kk = 0; kk < 2; ++kk)
            #pragma unroll
            for (int nt = 0; nt < 4; ++nt) {
                int kvrow = nt*16 + r;
                fr[kk][nt] = *(const bf16x8*)((const char*)Ks + kvrow*128 +
                                              ((kk*64 + g*16) ^ ((kvrow & 7) << 4)));
            }

        // scores SWAPPED: D[kv][q] = mfma(K, Q); lane holds q=r, kv = nt*16+g*4+reg
        f32x4 sc[2][4];
        #pragma unroll
        for (int grp = 0; grp < 2; ++grp) {
            sc[grp][0]=zf; sc[grp][1]=zf; sc[grp][2]=zf; sc[grp][3]=zf;
            #pragma unroll
            for (int kk = 0; kk < 2; ++kk)
                #pragma unroll
                for (int nt = 0; nt < 4; ++nt)
                    sc[grp][nt] = __builtin_amdgcn_mfma_f32_16x16x32_bf16(
                        fr[kk][nt], qf[grp][kk], sc[grp][nt], 0, 0, 0);
        }

        // softmax per group (row-local, 2 shuffles)
        #pragma unroll
        for (int grp = 0; grp < 2; ++grp) {
            float pmax = sc[grp][0][0];
            #pragma unroll
            for (int nt = 0; nt < 4; ++nt)
                #pragma unroll
                for (int reg = 0; reg < 4; ++reg)
                    pmax = fmaxf(pmax, sc[grp][nt][reg]);
            pmax = fmaxf(pmax, __shfl_xor(pmax, 16));
            pmax = fmaxf(pmax, __shfl_xor(pmax, 32));

            if (__any(pmax > m_run[grp] + 8.0f)) {   // defer-max: P bounded by 2^8
                float mn = fmaxf(m_run[grp], pmax);
                float corr = fexp2(m_run[grp] - mn);
                l_run[grp] *= corr;
                #pragma unroll
                for (int nt2 = 0; nt2 < 4; ++nt2) {
                    o[grp][nt2][0] *= corr; o[grp][nt2][1] *= corr;
                    o[grp][nt2][2] *= corr; o[grp][nt2][3] *= corr;
                }
                m_run[grp] = mn;
            }

            float lsum = 0.f;
            #pragma unroll
            for (int nt = 0; nt < 4; ++nt) {
                #pragma unroll
                for (int reg = 0; reg < 4; ++reg) {
                    float p = fexp2(sc[grp][nt][reg] - m_run[grp]);
                    sc[grp][nt][reg] = p;
                    lsum += p;
                }
            }
            lsum += __shfl_xor(lsum, 16);
            lsum += __shfl_xor(lsum, 32);
            l_run[grp] += lsum;
        }

        // V fragments once per wave (overwrite fr), shared by both groups
        #pragma unroll
        for (int kk = 0; kk < 2; ++kk)
            #pragma unroll
            for (int nt2 = 0; nt2 < 4; ++nt2) {
                int dh = nt2*16 + r;
                fr[kk][nt2] = *(const bf16x8*)((const char*)Vs + dh*128 +
                                               ((kk*64 + g*16) ^ ((dh & 7) << 4)));
            }

        // per group: pack P -> Ps[w] (reused), then PV: O^T[dh][q] += mfma(V^T, P)
        ushort* pw = Ps[w];
        #pragma unroll
        for (int grp = 0; grp < 2; ++grp) {
            #pragma unroll
            for (int nt = 0; nt < 4; ++nt) {
                uint u0 = cvtpk(sc[grp][nt][0], sc[grp][nt][1]);
                uint u1 = cvtpk(sc[grp][nt][2], sc[grp][nt][3]);
                int chunk = (2*nt + (g >> 1)) ^ (r & 7);
                *(uint2*)((char*)pw + r*128 + (chunk << 4) + ((g & 1)*8)) = make_uint2(u0, u1);
            }
            #pragma unroll
            for (int kk = 0; kk < 2; ++kk) {
                bf16x8 pa = *(const bf16x8*)((const char*)pw + r*128 +
                                             (((kk*4 + g) ^ (r & 7)) << 4));
                #pragma unroll
                for (int nt2 = 0; nt2 < 4; ++nt2)
                    o[grp][nt2] = __builtin_amdgcn_mfma_f32_16x16x32_bf16(
                        fr[kk][nt2], pa, o[grp][nt2], 0, 0, 0);
            }
        }
    }

    // epilogue: normalize, store heads bf16; fused msg = relu(heads @ w_mix)
    bf16x8 wmf[2][4];
    #pragma unroll
    for (int kk = 0; kk < 2; ++kk)
        #pragma unroll
        for (int nt = 0; nt < 4; ++nt)
            wmf[kk][nt] = *(const bf16x8*)(wmixT + (nt*16 + r)*64 + kk*32 + g*8);

    ushort* pw = Ps[w];
    #pragma unroll
    for (int grp = 0; grp < 2; ++grp) {
        float inv = 1.0f / l_run[grp];
        ushort* hp = headsbf + (bh*Sv + qt*64 + w*32 + grp*16 + r)*DHv;
        #pragma unroll
        for (int nt2 = 0; nt2 < 4; ++nt2) {
            uint u0 = cvtpk(o[grp][nt2][0]*inv, o[grp][nt2][1]*inv);
            uint u1 = cvtpk(o[grp][nt2][2]*inv, o[grp][nt2][3]*inv);
            *(uint2*)(hp + nt2*16 + g*4) = make_uint2(u0, u1);
            int chunk = (2*nt2 + (g >> 1)) ^ (r & 7);
            *(uint2*)((char*)pw + r*128 + (chunk << 4) + ((g & 1)*8)) = make_uint2(u0, u1);
        }
        f32x4 macc[4];
        const f32x4 zf2 = {0.f,0.f,0.f,0.f};
        macc[0]=zf2; macc[1]=zf2; macc[2]=zf2; macc[3]=zf2;
        #pragma unroll
        for (int kk = 0; kk < 2; ++kk) {
            bf16x8 pa = *(const bf16x8*)((const char*)pw + r*128 +
                                         (((kk*4 + g) ^ (r & 7)) << 4));
            #pragma unroll
            for (int nt = 0; nt < 4; ++nt)
                macc[nt] = __builtin_amdgcn_mfma_f32_16x16x32_bf16(wmf[kk][nt], pa, macc[nt], 0, 0, 0);
        }
        ushort* mp = msgbf + (bh*Sv + qt*64 + w*32 + grp*16 + r)*DHv;
        #pragma unroll
        for (int nt = 0; nt < 4; ++nt) {
            uint u0 = cvtpk(fmaxf(macc[nt][0], 0.f), fmaxf(macc[nt][1], 0.f));
            uint u1 = cvtpk(fmaxf(macc[nt][2], 0.f), fmaxf(macc[nt][3], 0.f));
            *(uint2*)(mp + nt*16 + g*4) = make_uint2(u0, u1);
        }
    }
}

// ---------------- out projection: [heads|msg] (K=2432) @ woTcat -> out fp32 ----------------
__global__ __launch_bounds__(256) void out_mfma(const ushort* __restrict__ headsbf,
                                                const ushort* __restrict__ msgbf,
                                                const ushort* __restrict__ woTcat,
                                                float* __restrict__ out) {
    const int mt = blockIdx.x, nt2 = blockIdx.y;
    const int m0 = mt*64, n0 = nt2*128;
    const int tid = threadIdx.x;
    const int w = tid >> 6, lane = tid & 63;
    const int g = lane >> 4, r = lane & 15;

    __shared__ char lds[8192 + 16384];
    char* As = lds;
    char* Bs = lds + 8192;

    const int b = m0 >> 11;
    const int s0 = m0 & 2047;

    f32x4 acc[8];
    const f32x4 zf = {0.f,0.f,0.f,0.f};
    #pragma unroll
    for (int n = 0; n < 8; ++n) acc[n] = zf;

    for (int ktile = 0; ktile < KK2/64; ++ktile) {
        const int hh = (ktile < H) ? ktile : ktile - H;
        const ushort* asrc = ((ktile < H) ? headsbf : msgbf) +
                             ((size_t)((size_t)b*H + hh)*Sv + s0)*DHv;
        __syncthreads();
        #pragma unroll
        for (int i = 0; i < 2; ++i) {
            int f = tid + i*256;
            int row = f >> 3, c = f & 7;
            *(bf16x8*)(As + row*128 + ((c*16) ^ ((row & 7) << 4))) =
                *(const bf16x8*)(asrc + (size_t)row*DHv + c*8);
        }
        #pragma unroll
        for (int i = 0; i < 4; ++i) {
            int f = tid + i*256;
            int row = f >> 3, c = f & 7;
            *(bf16x8*)(Bs + row*128 + ((c*16) ^ ((row & 7) << 4))) =
                *(const bf16x8*)(woTcat + (size_t)(n0 + row)*KK2 + ktile*64 + c*8);
        }
        __syncthreads();
        #pragma unroll
        for (int kk = 0; kk < 2; ++kk) {
            int arow = w*16 + r;
            bf16x8 a = *(const bf16x8*)(As + arow*128 + (((kk*32 + g*8)*2) ^ ((arow & 7) << 4)));
            #pragma unroll
            for (int n = 0; n < 8; ++n) {
                int brow = n*16 + r;
                bf16x8 bfr = *(const bf16x8*)(Bs + brow*128 + (((kk*32 + g*8)*2) ^ ((brow & 7) << 4)));
                acc[n] = __builtin_amdgcn_mfma_f32_16x16x32_bf16(a, bfr, acc[n], 0, 0, 0);
            }
        }
    }

    #pragma unroll
    for (int n = 0; n < 8; ++n) {
        #pragma unroll
        for (int reg = 0; reg < 4; ++reg) {
            int grow = m0 + w*16 + g*4 + reg;
            out[(size_t)grow*Dv + n0 + n*16 + r] = acc[n][reg];
        }
    }
}

extern "C" void kernel_launch(void* const* d_in, const int* in_sizes, int n_in,
                              void* d_out, int out_size, void* d_ws, size_t ws_size,
                              hipStream_t stream) {
    const float* x      = (const float*)d_in[0];
    const float* coords = (const float*)d_in[1];
    const float* w_q    = (const float*)d_in[2];
    const float* w_k    = (const float*)d_in[3];
    const float* w_v    = (const float*)d_in[4];
    const float* wb1    = (const float*)d_in[5];
    const float* bb1    = (const float*)d_in[6];
    const float* wb2    = (const float*)d_in[7];
    const float* bb2    = (const float*)d_in[8];
    const float* w_mix  = (const float*)d_in[9];
    const float* adj    = (const float*)d_in[10];
    const float* w_o    = (const float*)d_in[11];

    char* ws = (char*)d_ws;
    const size_t QKV_BYTES = (size_t)Bv*H*Sv*DHv*2;   // 9,961,472
    const size_t XBF_BYTES = (size_t)Bv*Sv*Dv*2;      // 8,388,608
    const size_t WPK_BYTES = (size_t)H*192*Dv*2;      // 7,471,104

    size_t off = 0;
    float*  biasp = (float*)(ws + off);  off += 32768;   // bias partials [4][H][64]
    ushort* qbf   = (ushort*)(ws + off); off += QKV_BYTES;
    ushort* kbf   = (ushort*)(ws + off); off += QKV_BYTES;
    ushort* vtbf  = (ushort*)(ws + off); off += QKV_BYTES;
    ushort* hdbf  = (ushort*)(ws + off); off += QKV_BYTES;
    ushort* xbf   = (ushort*)(ws + off);
    ushort* msgbf = xbf;                              // aliases xbf+wpkT (dead after qkv)
    off += XBF_BYTES;
    ushort* wpkT  = (ushort*)(ws + off); off += WPK_BYTES;
    ushort* wmixT = (ushort*)(ws + off); off += 8192;
    ushort* woTc  = (ushort*)(ws + off); off += (size_t)Dv*KK2*2;
    float*  out   = (float*)d_out;

    prep_misc<<<PREP_N, 256, 0, stream>>>(x, w_q, w_k, w_v, w_o, adj, w_mix,
                                          xbf, wpkT, wmixT, woTc);
    bias_part_kernel<<<dim3(4, H), 256, 0, stream>>>(coords, wb1, bb1, wb2, bb2, biasp);
    qkv_mfma<<<dim3(64, H), 256, 0, stream>>>(xbf, wpkT, biasp, qbf, kbf, vtbf);
    attn_mfma<<<1216, 128, 0, stream>>>(qbf, kbf, vtbf, wmixT, hdbf, msgbf);
    out_mfma<<<dim3(64, 8), 256, 0, stream>>>(hdbf, msgbf, woTc, out);
}